// Round 3
// baseline (426.000 us; speedup 1.0000x reference)
//
#include <hip/hip_runtime.h>
#include <hip/hip_bf16.h>

// Problem constants (shapes fixed by the reference)
#define XS   2
#define NP   96
#define NLAY 3
// L_INPUT = 3, DIMS = (1,3,5,7), MAX_DIM = 7, NUM_CG = 4, NUM_CH = 16

// packed (rep,dim) index tables: 16 = 1+3+5+7 entries
__constant__ int P2R_c[16] = {0, 1,1,1, 2,2,2,2,2, 3,3,3,3,3,3,3};
__constant__ int P2D_c[16] = {0, 0,1,2, 0,1,2,3,4, 0,1,2,3,4,5,6};
__constant__ int DIMS_c[4] = {1,3,5,7};
__constant__ int OFF_c[4]  = {0,1,4,9};

__device__ inline float2 cmul(float2 a, float2 b){
    return make_float2(a.x*b.x - a.y*b.y, a.x*b.y + a.y*b.x);
}
__device__ inline float2 cmadd(float2 acc, float2 a, float2 b){
    acc.x += a.x*b.x - a.y*b.y;
    acc.y += a.x*b.y + a.y*b.x;
    return acc;
}

// One prep kernel, three flat ranges:
//  [0, 2352)            cgf[k][qr][s][t] = sum_g cg[g,3,s,3,t,q,r]*f[k,q,g]
//  [2352, 2352+16384)   PK[qr][ls][mt][g] = cg[g,l,s,m,t,q,r]  (dense repack)
//  [18736, 18736+49152) pack V -> Vp[x][j][mt16][c16]
#define PREP_TOTAL (2352 + 16384 + 49152)
__global__ void prep_kernel(const float* __restrict__ cg,
                            const float* __restrict__ f,
                            const float* __restrict__ Vin,
                            float* __restrict__ cgf,
                            float* __restrict__ PK,
                            float* __restrict__ Vp){
    int idx = blockIdx.x*256 + threadIdx.x;
    if (idx < 2352){
        int k  = idx / (16*49);
        int rem = idx % (16*49);
        int qr = rem / 49;
        int st = rem % 49;
        int s = st / 7, t = st % 7;
        int q = P2R_c[qr], r = P2D_c[qr];
        float2 acc = make_float2(0.f, 0.f);
        for (int g = 0; g < 4; ++g){
            const float* cgp = cg + (((((((size_t)g*4+3)*7 + s)*4 + 3)*7 + t)*4 + q)*7 + r)*2;
            const float* fp  = f + ((k*4 + q)*4 + g)*2;
            acc = cmadd(acc, make_float2(cgp[0], cgp[1]), make_float2(fp[0], fp[1]));
        }
        cgf[idx*2]   = acc.x;
        cgf[idx*2+1] = acc.y;
    } else if (idx < 2352 + 16384){
        int id = idx - 2352;           // = ((qr*16+ls)*16+mt)*4+g
        int g  = id & 3;
        int mt = (id >> 2) & 15;
        int ls = (id >> 6) & 15;
        int qr = (id >> 10) & 15;
        int l = P2R_c[ls], s = P2D_c[ls];
        int m = P2R_c[mt], t = P2D_c[mt];
        int q = P2R_c[qr], r = P2D_c[qr];
        size_t co = (((((((size_t)g*4 + l)*7 + s)*4 + m)*7 + t)*4 + q)*7 + r);
        PK[id*2]   = cg[co*2];
        PK[id*2+1] = cg[co*2+1];
    } else if (idx < PREP_TOTAL){
        int id = idx - 18736;          // = (xj*16+mt)*16+c
        int c  = id & 15;
        int mt = (id >> 4) & 15;
        int xj = id >> 8;
        int m = P2R_c[mt], t = P2D_c[mt];
        const float* p = Vin + ((((size_t)xj*4 + m)*16 + c)*7 + t)*2;
        Vp[id*2]   = p[0];
        Vp[id*2+1] = p[1];
    }
}

// One layer, one block per (x,i), 1024 threads.
__global__ __launch_bounds__(1024)
void layer_kernel(const float* __restrict__ X,
                  const float* __restrict__ cgf_k,  // [16][49] complex
                  const float* __restrict__ PK,     // [qr][ls][mt][g] complex
                  const float* __restrict__ W_k,    // [q][c][g][d] complex
                  const float* __restrict__ Vin,    // packed [x][j][mt][c]
                  float* __restrict__ Vout)         // packed [x][i][qr][d]
{
    __shared__ float2 filt_s[NP][16];     // 12288 B
    __shared__ float2 T_s[16][256];       // 32768 B  [ls][mt*16+c]
    __shared__ char   scratch_raw[11648]; // union region
    float2 (*dX_s)[7] = (float2(*)[7])scratch_raw;       // 96*7*8  = 5376 B
    float2 *cgf_s     = (float2*)(scratch_raw + 5376);   // 784*8   = 6272 B
    float2 *S_s       = (float2*)scratch_raw;            // [g][qr][c] 1024*8 = 8192 B (after phase 0)

    const int tid = threadIdx.x;
    const int x = blockIdx.x / NP, i = blockIdx.x % NP;

    // phase -1/0a: stage cgf + dX in LDS
    if (tid < 784) cgf_s[tid] = ((const float2*)cgf_k)[tid];
    if (tid < NP*7){
        int j = tid / 7, s = tid % 7;
        const float* Xj = X + (((size_t)x*NP + j)*7 + s)*2;
        const float* Xi = X + (((size_t)x*NP + i)*7 + s)*2;
        dX_s[j][s] = make_float2(Xj[0]-Xi[0], Xj[1]-Xi[1]);
    }
    __syncthreads();

    // phase 0b: filt[j][qr] = [q==3]*dX[r] + sum_s dX[s]*(sum_t cgf[qr][s][t]*dX[t])
    for (int e = tid; e < NP*16; e += 1024){
        int j = e >> 4, qr = e & 15;
        const float2* cb = cgf_s + qr*49;
        float2 acc = make_float2(0.f, 0.f);
        #pragma unroll
        for (int s = 0; s < 7; ++s){
            float2 inner = make_float2(0.f, 0.f);
            #pragma unroll
            for (int t = 0; t < 7; ++t)
                inner = cmadd(inner, cb[s*7 + t], dX_s[j][t]);
            acc = cmadd(acc, dX_s[j][s], inner);
        }
        if (qr >= 9){ float2 dv = dX_s[j][qr-9]; acc.x += dv.x; acc.y += dv.y; }
        filt_s[j][qr] = acc;
    }
    __syncthreads();

    // phase 1: T[ls][mtc] = sum_j filt[j][ls]*Vin[x][j][mtc]
    // 2-way j-split x 2-way ls-split: acc[8] = 16 VGPRs (fits 64-VGPR budget, no spill)
    {
        const int sel = tid >> 8;      // 0..3
        const int jg  = sel & 1;       // j half
        const int lsh = sel >> 1;      // ls half
        const int mtc = tid & 255;
        const float2* Vb = (const float2*)Vin + (size_t)x*NP*256 + mtc;
        float2 acc[8];
        #pragma unroll
        for (int u = 0; u < 8; ++u) acc[u] = make_float2(0.f, 0.f);
        const int j0 = jg*48;
        #pragma unroll 4
        for (int jj = 0; jj < 48; ++jj){
            const int j = j0 + jj;
            float2 v = Vb[(size_t)j*256];
            const float2* frow = &filt_s[j][lsh*8];
            #pragma unroll
            for (int u = 0; u < 8; ++u)
                acc[u] = cmadd(acc[u], frow[u], v);
        }
        // 2-stage reduction into T_s (lsh halves are disjoint rows)
        if (jg == 0){
            #pragma unroll
            for (int u = 0; u < 8; ++u) T_s[lsh*8 + u][mtc] = acc[u];
        }
        __syncthreads();
        if (jg == 1){
            #pragma unroll
            for (int u = 0; u < 8; ++u){
                float2 tp = T_s[lsh*8 + u][mtc];
                tp.x += acc[u].x; tp.y += acc[u].y;
                T_s[lsh*8 + u][mtc] = tp;
            }
        }
        __syncthreads();
    }

    // phase 2: S[g][qr][c] = sum_{ls,mt} PK[qr][ls][mt][g]*T[ls][mt][c], 4-way ls-split
    {
        const int lsq = tid >> 8;      // 0..3
        const int qr  = (tid >> 4) & 15;
        const int c   = tid & 15;
        float2 accg[4];
        #pragma unroll
        for (int g = 0; g < 4; ++g) accg[g] = make_float2(0.f, 0.f);
        #pragma unroll
        for (int lo = 0; lo < 4; ++lo){
            const int ls = lsq*4 + lo;
            #pragma unroll 4
            for (int mt = 0; mt < 16; ++mt){
                float2 tv = T_s[ls][mt*16 + c];
                const float2* pk = (const float2*)PK + (((size_t)(qr*16 + ls)*16 + mt) << 2);
                accg[0] = cmadd(accg[0], pk[0], tv);
                accg[1] = cmadd(accg[1], pk[1], tv);
                accg[2] = cmadd(accg[2], pk[2], tv);
                accg[3] = cmadd(accg[3], pk[3], tv);
            }
        }
        // staged reduction into S_s (aliases dX/cgf scratch - both dead now)
        for (int g4 = 0; g4 < 4; ++g4){
            if (lsq == g4){
                if (g4 == 0){
                    #pragma unroll
                    for (int g = 0; g < 4; ++g) S_s[(g*16 + qr)*16 + c] = accg[g];
                } else {
                    #pragma unroll
                    for (int g = 0; g < 4; ++g){
                        float2 sp = S_s[(g*16 + qr)*16 + c];
                        sp.x += accg[g].x; sp.y += accg[g].y;
                        S_s[(g*16 + qr)*16 + c] = sp;
                    }
                }
            }
            __syncthreads();
        }
    }

    // phase 3: Vout[qr][d] = sum_{g,c} S[g][qr][c]*W[q][c][g][d]
    if (tid < 256){
        const int qr = tid >> 4, d = tid & 15;
        const int q = P2R_c[qr];
        float2 acc = make_float2(0.f, 0.f);
        const float2* Wb = (const float2*)W_k + (size_t)q*16*4*16 + d;
        #pragma unroll 4
        for (int c = 0; c < 16; ++c){
            #pragma unroll
            for (int g = 0; g < 4; ++g){
                float2 sv = S_s[(g*16 + qr)*16 + c];
                float2 wv = Wb[(c*4 + g)*16];
                acc = cmadd(acc, sv, wv);
            }
        }
        ((float2*)Vout)[(size_t)blockIdx.x*256 + tid] = acc;
    }
}

// unpack final packed V -> d_out (x,i,q,d,r,z), zeros at r >= DIMS[q]
__global__ void unpack_V_kernel(const float* __restrict__ Vp,
                                float* __restrict__ out){
    int idx = blockIdx.x*blockDim.x + threadIdx.x;
    if (idx >= XS*NP*4*16*7) return;
    int r  = idx % 7;
    int d  = (idx / 7) % 16;
    int q  = (idx / (7*16)) % 4;
    int xi = idx / (7*16*4);
    float2 v = make_float2(0.f, 0.f);
    if (r < DIMS_c[q]){
        v = ((const float2*)Vp)[(size_t)xi*256 + (OFF_c[q] + r)*16 + d];
    }
    ((float2*)out)[idx] = v;
}

extern "C" void kernel_launch(void* const* d_in, const int* in_sizes, int n_in,
                              void* d_out, int out_size, void* d_ws, size_t ws_size,
                              hipStream_t stream) {
    const float* X  = (const float*)d_in[0];
    // d_in[1] is 'l' (always 3, hardcoded)
    const float* V  = (const float*)d_in[2];
    const float* cg = (const float*)d_in[3];
    const float* f  = (const float*)d_in[4];
    const float* W  = (const float*)d_in[5];
    // d_in[6] is C4 (plain complex product, hardcoded)

    float* ws    = (float*)d_ws;
    float* cgf   = ws;                        // 2352 cplx = 4704 floats
    float* PK    = ws + 4704;                 // 16384 cplx = 32768 floats
    float* VbufA = ws + 4704 + 32768;         // 49152 cplx = 98304 floats
    float* VbufB = VbufA + XS*NP*256*2;       // 98304 floats

    prep_kernel<<<(PREP_TOTAL + 255)/256, 256, 0, stream>>>(cg, f, V, cgf, PK, VbufA);

    float* bufs[2] = {VbufA, VbufB};
    int cur = 0;
    for (int k = 0; k < NLAY; ++k){
        const float* cgf_k = cgf + (size_t)k*16*49*2;
        const float* W_k   = W   + (size_t)k*4*16*4*16*2;
        layer_kernel<<<XS*NP, 1024, 0, stream>>>(X, cgf_k, PK, W_k,
                                                 bufs[cur], bufs[cur^1]);
        cur ^= 1;
    }
    unpack_V_kernel<<<(XS*NP*4*16*7 + 255)/256, 256, 0, stream>>>(bufs[cur], (float*)d_out);
}

// Round 4
// 282.594 us; speedup vs baseline: 1.5075x; 1.5075x over previous
//
#include <hip/hip_runtime.h>
#include <hip/hip_bf16.h>

// Problem constants (shapes fixed by the reference)
#define XS   2
#define NP   96
#define NLAY 3
// L_INPUT = 3, DIMS = (1,3,5,7), MAX_DIM = 7, NUM_CG = 4, NUM_CH = 16

// packed (rep,dim) index tables: 16 = 1+3+5+7 entries
__constant__ int P2R_c[16] = {0, 1,1,1, 2,2,2,2,2, 3,3,3,3,3,3,3};
__constant__ int P2D_c[16] = {0, 0,1,2, 0,1,2,3,4, 0,1,2,3,4,5,6};
__constant__ int DIMS_c[4] = {1,3,5,7};
__constant__ int OFF_c[4]  = {0,1,4,9};

__device__ inline float2 cmul(float2 a, float2 b){
    return make_float2(a.x*b.x - a.y*b.y, a.x*b.y + a.y*b.x);
}
__device__ inline float2 cmadd(float2 acc, float2 a, float2 b){
    acc.x += a.x*b.x - a.y*b.y;
    acc.y += a.x*b.y + a.y*b.x;
    return acc;
}

// One prep kernel, three flat ranges:
//  [0, 2352)            cgf[k][qr][s][t] = sum_g cg[g,3,s,3,t,q,r]*f[k,q,g]
//  [2352, 2352+16384)   PK[qr][ls][mt][g] = cg[g,l,s,m,t,q,r]  (dense repack)
//  [18736, 18736+49152) pack V -> Vp[x][j][mt16][c16]
#define PREP_TOTAL (2352 + 16384 + 49152)
__global__ void prep_kernel(const float* __restrict__ cg,
                            const float* __restrict__ f,
                            const float* __restrict__ Vin,
                            float* __restrict__ cgf,
                            float* __restrict__ PK,
                            float* __restrict__ Vp){
    int idx = blockIdx.x*256 + threadIdx.x;
    if (idx < 2352){
        int k  = idx / (16*49);
        int rem = idx % (16*49);
        int qr = rem / 49;
        int st = rem % 49;
        int s = st / 7, t = st % 7;
        int q = P2R_c[qr], r = P2D_c[qr];
        float2 acc = make_float2(0.f, 0.f);
        for (int g = 0; g < 4; ++g){
            const float* cgp = cg + (((((((size_t)g*4+3)*7 + s)*4 + 3)*7 + t)*4 + q)*7 + r)*2;
            const float* fp  = f + ((k*4 + q)*4 + g)*2;
            acc = cmadd(acc, make_float2(cgp[0], cgp[1]), make_float2(fp[0], fp[1]));
        }
        cgf[idx*2]   = acc.x;
        cgf[idx*2+1] = acc.y;
    } else if (idx < 2352 + 16384){
        int id = idx - 2352;           // = ((qr*16+ls)*16+mt)*4+g
        int g  = id & 3;
        int mt = (id >> 2) & 15;
        int ls = (id >> 6) & 15;
        int qr = (id >> 10) & 15;
        int l = P2R_c[ls], s = P2D_c[ls];
        int m = P2R_c[mt], t = P2D_c[mt];
        int q = P2R_c[qr], r = P2D_c[qr];
        size_t co = (((((((size_t)g*4 + l)*7 + s)*4 + m)*7 + t)*4 + q)*7 + r);
        PK[id*2]   = cg[co*2];
        PK[id*2+1] = cg[co*2+1];
    } else if (idx < PREP_TOTAL){
        int id = idx - 18736;          // = (xj*16+mt)*16+c
        int c  = id & 15;
        int mt = (id >> 4) & 15;
        int xj = id >> 8;
        int m = P2R_c[mt], t = P2D_c[mt];
        const float* p = Vin + ((((size_t)xj*4 + m)*16 + c)*7 + t)*2;
        Vp[id*2]   = p[0];
        Vp[id*2+1] = p[1];
    }
}

// One layer, one block per (x,i), 1024 threads.
// __launch_bounds__(1024, 4): 4 waves/EU min = 1 block/CU -> 128-VGPR budget.
// (The default cap was 64 VGPRs -> massive scratch spill: 183 MB HBM writes/dispatch.)
__global__ __launch_bounds__(1024, 4)
void layer_kernel(const float* __restrict__ X,
                  const float* __restrict__ cgf_k,  // [16][49] complex
                  const float* __restrict__ PK,     // [qr][ls][mt][g] complex
                  const float* __restrict__ W_k,    // [q][c][g][d] complex
                  const float* __restrict__ Vin,    // packed [x][j][mt][c]
                  float* __restrict__ Vout)         // packed [x][i][qr][d]
{
    __shared__ float2 filt_s[NP][16];     // 12288 B
    __shared__ float2 T_s[16][256];       // 32768 B  [ls][mt*16+c]
    __shared__ char   scratch_raw[11648]; // union region
    float2 (*dX_s)[7] = (float2(*)[7])scratch_raw;       // 96*7*8  = 5376 B
    float2 *cgf_s     = (float2*)(scratch_raw + 5376);   // 784*8   = 6272 B
    float2 *S_s       = (float2*)scratch_raw;            // [g][qr][c] 1024*8 = 8192 B (after phase 0)

    const int tid = threadIdx.x;
    const int x = blockIdx.x / NP, i = blockIdx.x % NP;

    // phase -1/0a: stage cgf + dX in LDS
    if (tid < 784) cgf_s[tid] = ((const float2*)cgf_k)[tid];
    if (tid < NP*7){
        int j = tid / 7, s = tid % 7;
        const float* Xj = X + (((size_t)x*NP + j)*7 + s)*2;
        const float* Xi = X + (((size_t)x*NP + i)*7 + s)*2;
        dX_s[j][s] = make_float2(Xj[0]-Xi[0], Xj[1]-Xi[1]);
    }
    __syncthreads();

    // phase 0b: filt[j][qr] = [q==3]*dX[r] + sum_s dX[s]*(sum_t cgf[qr][s][t]*dX[t])
    for (int e = tid; e < NP*16; e += 1024){
        int j = e >> 4, qr = e & 15;
        const float2* cb = cgf_s + qr*49;
        float2 acc = make_float2(0.f, 0.f);
        #pragma unroll
        for (int s = 0; s < 7; ++s){
            float2 inner = make_float2(0.f, 0.f);
            #pragma unroll
            for (int t = 0; t < 7; ++t)
                inner = cmadd(inner, cb[s*7 + t], dX_s[j][t]);
            acc = cmadd(acc, dX_s[j][s], inner);
        }
        if (qr >= 9){ float2 dv = dX_s[j][qr-9]; acc.x += dv.x; acc.y += dv.y; }
        filt_s[j][qr] = acc;
    }
    __syncthreads();

    // phase 1: T[ls][mtc] = sum_j filt[j][ls]*Vin[x][j][mtc], 4-way j-split,
    // acc[16] = 32 VGPRs (fits the 128-VGPR budget; one V load per 16 cmadds)
    {
        const int jg  = tid >> 8;      // 0..3
        const int mtc = tid & 255;
        const float2* Vb = (const float2*)Vin + (size_t)x*NP*256 + mtc;
        float2 acc[16];
        #pragma unroll
        for (int ls = 0; ls < 16; ++ls) acc[ls] = make_float2(0.f, 0.f);
        const int j0 = jg*24;
        #pragma unroll 4
        for (int jj = 0; jj < 24; ++jj){
            const int j = j0 + jj;
            float2 v = Vb[(size_t)j*256];
            const float2* fr = filt_s[j];
            #pragma unroll
            for (int ls = 0; ls < 16; ++ls)
                acc[ls] = cmadd(acc[ls], fr[ls], v);
        }
        // staged reduction into T_s
        for (int g = 0; g < 4; ++g){
            if (jg == g){
                if (g == 0){
                    #pragma unroll
                    for (int ls = 0; ls < 16; ++ls) T_s[ls][mtc] = acc[ls];
                } else {
                    #pragma unroll
                    for (int ls = 0; ls < 16; ++ls){
                        float2 tp = T_s[ls][mtc];
                        tp.x += acc[ls].x; tp.y += acc[ls].y;
                        T_s[ls][mtc] = tp;
                    }
                }
            }
            __syncthreads();
        }
    }

    // phase 2: S[g][qr][c] = sum_{ls,mt} PK[qr][ls][mt][g]*T[ls][mt][c], 4-way ls-split
    {
        const int lsq = tid >> 8;      // 0..3
        const int qr  = (tid >> 4) & 15;
        const int c   = tid & 15;
        float2 accg[4];
        #pragma unroll
        for (int g = 0; g < 4; ++g) accg[g] = make_float2(0.f, 0.f);
        #pragma unroll
        for (int lo = 0; lo < 4; ++lo){
            const int ls = lsq*4 + lo;
            #pragma unroll 4
            for (int mt = 0; mt < 16; ++mt){
                float2 tv = T_s[ls][mt*16 + c];
                const float2* pk = (const float2*)PK + (((size_t)(qr*16 + ls)*16 + mt) << 2);
                accg[0] = cmadd(accg[0], pk[0], tv);
                accg[1] = cmadd(accg[1], pk[1], tv);
                accg[2] = cmadd(accg[2], pk[2], tv);
                accg[3] = cmadd(accg[3], pk[3], tv);
            }
        }
        // staged reduction into S_s (aliases dX/cgf scratch - both dead now)
        for (int g4 = 0; g4 < 4; ++g4){
            if (lsq == g4){
                if (g4 == 0){
                    #pragma unroll
                    for (int g = 0; g < 4; ++g) S_s[(g*16 + qr)*16 + c] = accg[g];
                } else {
                    #pragma unroll
                    for (int g = 0; g < 4; ++g){
                        float2 sp = S_s[(g*16 + qr)*16 + c];
                        sp.x += accg[g].x; sp.y += accg[g].y;
                        S_s[(g*16 + qr)*16 + c] = sp;
                    }
                }
            }
            __syncthreads();
        }
    }

    // phase 3: Vout[qr][d] = sum_{g,c} S[g][qr][c]*W[q][c][g][d]
    if (tid < 256){
        const int qr = tid >> 4, d = tid & 15;
        const int q = P2R_c[qr];
        float2 acc = make_float2(0.f, 0.f);
        const float2* Wb = (const float2*)W_k + (size_t)q*16*4*16 + d;
        #pragma unroll 4
        for (int c = 0; c < 16; ++c){
            #pragma unroll
            for (int g = 0; g < 4; ++g){
                float2 sv = S_s[(g*16 + qr)*16 + c];
                float2 wv = Wb[(c*4 + g)*16];
                acc = cmadd(acc, sv, wv);
            }
        }
        ((float2*)Vout)[(size_t)blockIdx.x*256 + tid] = acc;
    }
}

// unpack final packed V -> d_out (x,i,q,d,r,z), zeros at r >= DIMS[q]
__global__ void unpack_V_kernel(const float* __restrict__ Vp,
                                float* __restrict__ out){
    int idx = blockIdx.x*blockDim.x + threadIdx.x;
    if (idx >= XS*NP*4*16*7) return;
    int r  = idx % 7;
    int d  = (idx / 7) % 16;
    int q  = (idx / (7*16)) % 4;
    int xi = idx / (7*16*4);
    float2 v = make_float2(0.f, 0.f);
    if (r < DIMS_c[q]){
        v = ((const float2*)Vp)[(size_t)xi*256 + (OFF_c[q] + r)*16 + d];
    }
    ((float2*)out)[idx] = v;
}

extern "C" void kernel_launch(void* const* d_in, const int* in_sizes, int n_in,
                              void* d_out, int out_size, void* d_ws, size_t ws_size,
                              hipStream_t stream) {
    const float* X  = (const float*)d_in[0];
    // d_in[1] is 'l' (always 3, hardcoded)
    const float* V  = (const float*)d_in[2];
    const float* cg = (const float*)d_in[3];
    const float* f  = (const float*)d_in[4];
    const float* W  = (const float*)d_in[5];
    // d_in[6] is C4 (plain complex product, hardcoded)

    float* ws    = (float*)d_ws;
    float* cgf   = ws;                        // 2352 cplx = 4704 floats
    float* PK    = ws + 4704;                 // 16384 cplx = 32768 floats
    float* VbufA = ws + 4704 + 32768;         // 49152 cplx = 98304 floats
    float* VbufB = VbufA + XS*NP*256*2;       // 98304 floats

    prep_kernel<<<(PREP_TOTAL + 255)/256, 256, 0, stream>>>(cg, f, V, cgf, PK, VbufA);

    float* bufs[2] = {VbufA, VbufB};
    int cur = 0;
    for (int k = 0; k < NLAY; ++k){
        const float* cgf_k = cgf + (size_t)k*16*49*2;
        const float* W_k   = W   + (size_t)k*4*16*4*16*2;
        layer_kernel<<<XS*NP, 1024, 0, stream>>>(X, cgf_k, PK, W_k,
                                                 bufs[cur], bufs[cur^1]);
        cur ^= 1;
    }
    unpack_V_kernel<<<(XS*NP*4*16*7 + 255)/256, 256, 0, stream>>>(bufs[cur], (float*)d_out);
}

// Round 5
// 202.835 us; speedup vs baseline: 2.1002x; 1.3932x over previous
//
#include <hip/hip_runtime.h>
#include <hip/hip_bf16.h>

// Problem constants (shapes fixed by the reference)
#define XS   2
#define NP   96
#define NLAY 3
// L_INPUT = 3, DIMS = (1,3,5,7), MAX_DIM = 7, NUM_CG = 4, NUM_CH = 16

// packed (rep,dim) index tables: 16 = 1+3+5+7 entries
__constant__ int P2R_c[16] = {0, 1,1,1, 2,2,2,2,2, 3,3,3,3,3,3,3};
__constant__ int P2D_c[16] = {0, 0,1,2, 0,1,2,3,4, 0,1,2,3,4,5,6};
__constant__ int DIMS_c[4] = {1,3,5,7};
__constant__ int OFF_c[4]  = {0,1,4,9};

__device__ inline float2 cmadd(float2 acc, float2 a, float2 b){
    acc.x += a.x*b.x - a.y*b.y;
    acc.y += a.x*b.y + a.y*b.x;
    return acc;
}

// One prep kernel, three flat ranges:
//  [0, 2352)            cgf[k][qr][s][t] = sum_g cg[g,3,s,3,t,q,r]*f[k,q,g]
//  [2352, 2352+16384)   PK[qr][ls][mt][g] = cg[g,l,s,m,t,q,r]  (dense repack)
//  [18736, 18736+49152) pack V -> Vp[x][j][mt16][c16]
#define PREP_TOTAL (2352 + 16384 + 49152)
__global__ void prep_kernel(const float* __restrict__ cg,
                            const float* __restrict__ f,
                            const float* __restrict__ Vin,
                            float* __restrict__ cgf,
                            float* __restrict__ PK,
                            float* __restrict__ Vp){
    int idx = blockIdx.x*256 + threadIdx.x;
    if (idx < 2352){
        int k  = idx / (16*49);
        int rem = idx % (16*49);
        int qr = rem / 49;
        int st = rem % 49;
        int s = st / 7, t = st % 7;
        int q = P2R_c[qr], r = P2D_c[qr];
        float2 acc = make_float2(0.f, 0.f);
        for (int g = 0; g < 4; ++g){
            const float* cgp = cg + (((((((size_t)g*4+3)*7 + s)*4 + 3)*7 + t)*4 + q)*7 + r)*2;
            const float* fp  = f + ((k*4 + q)*4 + g)*2;
            acc = cmadd(acc, make_float2(cgp[0], cgp[1]), make_float2(fp[0], fp[1]));
        }
        cgf[idx*2]   = acc.x;
        cgf[idx*2+1] = acc.y;
    } else if (idx < 2352 + 16384){
        int id = idx - 2352;           // = ((qr*16+ls)*16+mt)*4+g
        int g  = id & 3;
        int mt = (id >> 2) & 15;
        int ls = (id >> 6) & 15;
        int qr = (id >> 10) & 15;
        int l = P2R_c[ls], s = P2D_c[ls];
        int m = P2R_c[mt], t = P2D_c[mt];
        int q = P2R_c[qr], r = P2D_c[qr];
        size_t co = (((((((size_t)g*4 + l)*7 + s)*4 + m)*7 + t)*4 + q)*7 + r);
        PK[id*2]   = cg[co*2];
        PK[id*2+1] = cg[co*2+1];
    } else if (idx < PREP_TOTAL){
        int id = idx - 18736;          // = (xj*16+mt)*16+c
        int c  = id & 15;
        int mt = (id >> 4) & 15;
        int xj = id >> 8;
        int m = P2R_c[mt], t = P2D_c[mt];
        const float* p = Vin + ((((size_t)xj*4 + m)*16 + c)*7 + t)*2;
        Vp[id*2]   = p[0];
        Vp[id*2+1] = p[1];
    }
}

// filt_kernel: one block per (x,i), 256 threads.
// filt_g[xi][j][ls] = [l==3]*dX[s] + sum_s dX[s]*(sum_t cgf[ls][s][t]*dX[t])
__global__ __launch_bounds__(256)
void filt_kernel(const float* __restrict__ X,
                 const float* __restrict__ cgf_k,   // [16][49] complex
                 float* __restrict__ filt_g)        // [xi][96][16] complex
{
    __shared__ float2 cgf_s[784];      // 6272 B
    __shared__ float2 dX_s[NP][7];     // 5376 B

    const int tid = threadIdx.x;
    const int xi = blockIdx.x;
    const int x = xi / NP, i = xi % NP;

    for (int u = tid; u < 784; u += 256) cgf_s[u] = ((const float2*)cgf_k)[u];
    for (int e = tid; e < NP*7; e += 256){
        int j = e / 7, s = e % 7;
        const float* Xj = X + (((size_t)x*NP + j)*7 + s)*2;
        const float* Xi = X + (((size_t)x*NP + i)*7 + s)*2;
        dX_s[j][s] = make_float2(Xj[0]-Xi[0], Xj[1]-Xi[1]);
    }
    __syncthreads();

    float2* out = (float2*)filt_g + (size_t)xi*NP*16;
    for (int e = tid; e < NP*16; e += 256){
        int j = e >> 4, qr = e & 15;
        const float2* cb = cgf_s + qr*49;
        float2 acc = make_float2(0.f, 0.f);
        #pragma unroll
        for (int s = 0; s < 7; ++s){
            float2 inner = make_float2(0.f, 0.f);
            #pragma unroll
            for (int t = 0; t < 7; ++t)
                inner = cmadd(inner, cb[s*7 + t], dX_s[j][t]);
            acc = cmadd(acc, dX_s[j][s], inner);
        }
        if (qr >= 9){ float2 dv = dX_s[j][qr-9]; acc.x += dv.x; acc.y += dv.y; }
        out[e] = acc;
    }
}

// T_kernel: grid 768 = (xi, mtc-quarter), 256 threads (4 jg x 64 mtc_local).
// T_g[xi][ls][mtc] = sum_j filt[xi][j][ls] * Vin[x][j][mtc]
__global__ __launch_bounds__(256)
void T_kernel(const float* __restrict__ filt_g,
              const float* __restrict__ Vin,       // packed [x][j][mtc]
              float* __restrict__ T_g)             // [xi][16][256] complex
{
    __shared__ float2 filt_s[NP][16];  // 12288 B
    __shared__ float2 Tred[16][64];    // 8192 B

    const int tid = threadIdx.x;
    const int bid = blockIdx.x;
    const int xi  = bid >> 2;
    const int qtr = bid & 3;
    const int x   = xi / NP;

    // stage this xi's filter block (24 KB of global, L2-hit) into LDS
    {
        const float2* src = (const float2*)filt_g + (size_t)xi*NP*16;
        float2* dst = &filt_s[0][0];
        for (int e = tid; e < NP*16; e += 256) dst[e] = src[e];
    }
    __syncthreads();

    const int jg    = tid >> 6;       // 0..3
    const int mtc_l = tid & 63;
    const float2* Vb = (const float2*)Vin + (size_t)x*NP*256 + qtr*64 + mtc_l;

    float2 acc[16];
    #pragma unroll
    for (int u = 0; u < 16; ++u) acc[u] = make_float2(0.f, 0.f);
    const int j0 = jg*24;
    #pragma unroll 4
    for (int jj = 0; jj < 24; ++jj){
        const int j = j0 + jj;
        float2 v = Vb[(size_t)j*256];
        const float2* fr = filt_s[j];
        #pragma unroll
        for (int ls = 0; ls < 16; ++ls)
            acc[ls] = cmadd(acc[ls], fr[ls], v);
    }
    // 4-stage reduction over jg into Tred
    for (int g = 0; g < 4; ++g){
        if (jg == g){
            if (g == 0){
                #pragma unroll
                for (int ls = 0; ls < 16; ++ls) Tred[ls][mtc_l] = acc[ls];
            } else {
                #pragma unroll
                for (int ls = 0; ls < 16; ++ls){
                    float2 tp = Tred[ls][mtc_l];
                    tp.x += acc[ls].x; tp.y += acc[ls].y;
                    Tred[ls][mtc_l] = tp;
                }
            }
        }
        __syncthreads();
    }
    // write 16x64 tile: T_g[xi][ls][qtr*64 + ml]
    float2* To = (float2*)T_g + (size_t)xi*16*256 + qtr*64;
    for (int w = 0; w < 4; ++w){
        int e = tid + 256*w;
        int ls = e >> 6, ml = e & 63;
        To[(size_t)ls*256 + ml] = Tred[ls][ml];
    }
}

// S_kernel: one block per xi, 256 threads. Phases 2+3.
__global__ __launch_bounds__(256)
void S_kernel(const float* __restrict__ T_g,      // [xi][16][256] complex
              const float* __restrict__ PK,       // [qr][ls][mt][g] complex
              const float* __restrict__ W_k,      // [q][c][g][d] complex
              float* __restrict__ Vout)           // packed [xi][qr*16+d]
{
    __shared__ float2 T_s[16][256];    // 32768 B
    __shared__ float2 S_s[4*16*16];    // 8192 B

    const int tid = threadIdx.x;
    const int xi = blockIdx.x;

    {
        const float2* src = (const float2*)T_g + (size_t)xi*16*256;
        float2* dst = &T_s[0][0];
        for (int e = tid; e < 16*256; e += 256) dst[e] = src[e];
    }
    __syncthreads();

    // phase 2: S[g][qr][c] = sum_{ls,mt} PK[qr][ls][mt][g]*T[ls][mt][c]
    {
        const int qr = tid >> 4, c = tid & 15;
        float2 accg[4];
        #pragma unroll
        for (int g = 0; g < 4; ++g) accg[g] = make_float2(0.f, 0.f);
        for (int ls = 0; ls < 16; ++ls){
            const float2* pkr = (const float2*)PK + (((size_t)(qr*16 + ls)) << 6);
            #pragma unroll 4
            for (int mt = 0; mt < 16; ++mt){
                float2 tv = T_s[ls][mt*16 + c];
                const float2* pk = pkr + (mt << 2);
                accg[0] = cmadd(accg[0], pk[0], tv);
                accg[1] = cmadd(accg[1], pk[1], tv);
                accg[2] = cmadd(accg[2], pk[2], tv);
                accg[3] = cmadd(accg[3], pk[3], tv);
            }
        }
        #pragma unroll
        for (int g = 0; g < 4; ++g) S_s[(g*16 + qr)*16 + c] = accg[g];
    }
    __syncthreads();

    // phase 3: Vout[qr][d] = sum_{g,c} S[g][qr][c]*W[q][c][g][d]
    {
        const int qr = tid >> 4, d = tid & 15;
        const int q = P2R_c[qr];
        float2 acc = make_float2(0.f, 0.f);
        const float2* Wb = (const float2*)W_k + (size_t)q*16*4*16 + d;
        #pragma unroll 4
        for (int c = 0; c < 16; ++c){
            #pragma unroll
            for (int g = 0; g < 4; ++g){
                float2 sv = S_s[(g*16 + qr)*16 + c];
                float2 wv = Wb[(c*4 + g)*16];
                acc = cmadd(acc, sv, wv);
            }
        }
        ((float2*)Vout)[(size_t)xi*256 + tid] = acc;
    }
}

// unpack final packed V -> d_out (x,i,q,d,r,z), zeros at r >= DIMS[q]
__global__ void unpack_V_kernel(const float* __restrict__ Vp,
                                float* __restrict__ out){
    int idx = blockIdx.x*blockDim.x + threadIdx.x;
    if (idx >= XS*NP*4*16*7) return;
    int r  = idx % 7;
    int d  = (idx / 7) % 16;
    int q  = (idx / (7*16)) % 4;
    int xi = idx / (7*16*4);
    float2 v = make_float2(0.f, 0.f);
    if (r < DIMS_c[q]){
        v = ((const float2*)Vp)[(size_t)xi*256 + (OFF_c[q] + r)*16 + d];
    }
    ((float2*)out)[idx] = v;
}

extern "C" void kernel_launch(void* const* d_in, const int* in_sizes, int n_in,
                              void* d_out, int out_size, void* d_ws, size_t ws_size,
                              hipStream_t stream) {
    const float* X  = (const float*)d_in[0];
    // d_in[1] is 'l' (always 3, hardcoded)
    const float* V  = (const float*)d_in[2];
    const float* cg = (const float*)d_in[3];
    const float* f  = (const float*)d_in[4];
    const float* W  = (const float*)d_in[5];
    // d_in[6] is C4 (plain complex product, hardcoded)

    // ws layout (floats); total ~2.40M floats = 9.6 MB
    float* ws     = (float*)d_ws;
    float* cgf    = ws;                         // 4704
    float* PK     = cgf   + 4704;               // 32768
    float* VbufA  = PK    + 32768;              // 98304
    float* VbufB  = VbufA + 98304;              // 98304
    float* filt_g = VbufB + 98304;              // 192*96*16*2 = 589824
    float* T_g    = filt_g + 589824;            // 192*16*256*2 = 1572864

    prep_kernel<<<(PREP_TOTAL + 255)/256, 256, 0, stream>>>(cg, f, V, cgf, PK, VbufA);

    float* bufs[2] = {VbufA, VbufB};
    int cur = 0;
    for (int k = 0; k < NLAY; ++k){
        const float* cgf_k = cgf + (size_t)k*16*49*2;
        const float* W_k   = W   + (size_t)k*4*16*4*16*2;
        filt_kernel<<<XS*NP, 256, 0, stream>>>(X, cgf_k, filt_g);
        T_kernel<<<XS*NP*4, 256, 0, stream>>>(filt_g, bufs[cur], T_g);
        S_kernel<<<XS*NP, 256, 0, stream>>>(T_g, PK, W_k, bufs[cur^1]);
        cur ^= 1;
    }
    unpack_V_kernel<<<(XS*NP*4*16*7 + 255)/256, 256, 0, stream>>>(bufs[cur], (float*)d_out);
}

// Round 6
// 189.369 us; speedup vs baseline: 2.2496x; 1.0711x over previous
//
#include <hip/hip_runtime.h>
#include <hip/hip_bf16.h>

// Problem constants (shapes fixed by the reference)
#define XS   2
#define NP   96
#define NLAY 3
// L_INPUT = 3, DIMS = (1,3,5,7), MAX_DIM = 7, NUM_CG = 4, NUM_CH = 16

// packed (rep,dim) index tables: 16 = 1+3+5+7 entries
__constant__ int P2R_c[16] = {0, 1,1,1, 2,2,2,2,2, 3,3,3,3,3,3,3};
__constant__ int P2D_c[16] = {0, 0,1,2, 0,1,2,3,4, 0,1,2,3,4,5,6};
__constant__ int DIMS_c[4] = {1,3,5,7};
__constant__ int OFF_c[4]  = {0,1,4,9};

__device__ inline float2 cmadd(float2 acc, float2 a, float2 b){
    acc.x += a.x*b.x - a.y*b.y;
    acc.y += a.x*b.y + a.y*b.x;
    return acc;
}

// One prep kernel, three flat ranges:
//  [0, 2352)            cgf[k][qr][s][t] = sum_g cg[g,3,s,3,t,q,r]*f[k,q,g]
//  [2352, 2352+16384)   PK2[ls][mt][qr][g] = cg[g,l,s,m,t,q,r]  (g innermost -> 32B runs)
//  [18736, 18736+49152) pack V -> Vp[x][j][mt16][c16]
#define PREP_TOTAL (2352 + 16384 + 49152)
__global__ void prep_kernel(const float* __restrict__ cg,
                            const float* __restrict__ f,
                            const float* __restrict__ Vin,
                            float* __restrict__ cgf,
                            float* __restrict__ PK2,
                            float* __restrict__ Vp){
    int idx = blockIdx.x*256 + threadIdx.x;
    if (idx < 2352){
        int k  = idx / (16*49);
        int rem = idx % (16*49);
        int qr = rem / 49;
        int st = rem % 49;
        int s = st / 7, t = st % 7;
        int q = P2R_c[qr], r = P2D_c[qr];
        float2 acc = make_float2(0.f, 0.f);
        for (int g = 0; g < 4; ++g){
            const float* cgp = cg + (((((((size_t)g*4+3)*7 + s)*4 + 3)*7 + t)*4 + q)*7 + r)*2;
            const float* fp  = f + ((k*4 + q)*4 + g)*2;
            acc = cmadd(acc, make_float2(cgp[0], cgp[1]), make_float2(fp[0], fp[1]));
        }
        cgf[idx*2]   = acc.x;
        cgf[idx*2+1] = acc.y;
    } else if (idx < 2352 + 16384){
        int id = idx - 2352;           // = ((ls*16+mt)*16+qr)*4+g
        int g  = id & 3;
        int qr = (id >> 2) & 15;
        int mt = (id >> 6) & 15;
        int ls = (id >> 10) & 15;
        int l = P2R_c[ls], s = P2D_c[ls];
        int m = P2R_c[mt], t = P2D_c[mt];
        int q = P2R_c[qr], r = P2D_c[qr];
        size_t co = (((((((size_t)g*4 + l)*7 + s)*4 + m)*7 + t)*4 + q)*7 + r);
        PK2[id*2]   = cg[co*2];
        PK2[id*2+1] = cg[co*2+1];
    } else if (idx < PREP_TOTAL){
        int id = idx - 18736;          // = (xj*16+mt)*16+c
        int c  = id & 15;
        int mt = (id >> 4) & 15;
        int xj = id >> 8;
        int m = P2R_c[mt], t = P2D_c[mt];
        const float* p = Vin + ((((size_t)xj*4 + m)*16 + c)*7 + t)*2;
        Vp[id*2]   = p[0];
        Vp[id*2+1] = p[1];
    }
}

// filt_kernel: one block per (x,i), 256 threads.
__global__ __launch_bounds__(256)
void filt_kernel(const float* __restrict__ X,
                 const float* __restrict__ cgf_k,   // [16][49] complex
                 float* __restrict__ filt_g)        // [xi][96][16] complex
{
    __shared__ float2 cgf_s[784];      // 6272 B
    __shared__ float2 dX_s[NP][7];     // 5376 B

    const int tid = threadIdx.x;
    const int xi = blockIdx.x;
    const int x = xi / NP, i = xi % NP;

    for (int u = tid; u < 784; u += 256) cgf_s[u] = ((const float2*)cgf_k)[u];
    for (int e = tid; e < NP*7; e += 256){
        int j = e / 7, s = e % 7;
        const float* Xj = X + (((size_t)x*NP + j)*7 + s)*2;
        const float* Xi = X + (((size_t)x*NP + i)*7 + s)*2;
        dX_s[j][s] = make_float2(Xj[0]-Xi[0], Xj[1]-Xi[1]);
    }
    __syncthreads();

    float2* out = (float2*)filt_g + (size_t)xi*NP*16;
    for (int e = tid; e < NP*16; e += 256){
        int j = e >> 4, qr = e & 15;
        const float2* cb = cgf_s + qr*49;
        float2 acc = make_float2(0.f, 0.f);
        #pragma unroll
        for (int s = 0; s < 7; ++s){
            float2 inner = make_float2(0.f, 0.f);
            #pragma unroll
            for (int t = 0; t < 7; ++t)
                inner = cmadd(inner, cb[s*7 + t], dX_s[j][t]);
            acc = cmadd(acc, dX_s[j][s], inner);
        }
        if (qr >= 9){ float2 dv = dX_s[j][qr-9]; acc.x += dv.x; acc.y += dv.y; }
        out[e] = acc;
    }
}

// T_kernel: grid 768 = (xi, mtc-quarter), 256 threads (4 jg x 64 mtc_local).
// T_g[xi][ls][mtc] = sum_j filt[xi][j][ls] * Vin[x][j][mtc]
__global__ __launch_bounds__(256)
void T_kernel(const float* __restrict__ filt_g,
              const float* __restrict__ Vin,       // packed [x][j][mtc]
              float* __restrict__ T_g)             // [xi][16][256] complex
{
    __shared__ float2 filt_s[NP][16];  // 12288 B
    __shared__ float2 Tred[16][64];    // 8192 B

    const int tid = threadIdx.x;
    const int bid = blockIdx.x;
    const int xi  = bid >> 2;
    const int qtr = bid & 3;
    const int x   = xi / NP;

    {
        const float2* src = (const float2*)filt_g + (size_t)xi*NP*16;
        float2* dst = &filt_s[0][0];
        for (int e = tid; e < NP*16; e += 256) dst[e] = src[e];
    }
    __syncthreads();

    const int jg    = tid >> 6;       // 0..3
    const int mtc_l = tid & 63;
    const float2* Vb = (const float2*)Vin + (size_t)x*NP*256 + qtr*64 + mtc_l;

    float2 acc[16];
    #pragma unroll
    for (int u = 0; u < 16; ++u) acc[u] = make_float2(0.f, 0.f);
    const int j0 = jg*24;
    #pragma unroll 4
    for (int jj = 0; jj < 24; ++jj){
        const int j = j0 + jj;
        float2 v = Vb[(size_t)j*256];
        const float2* fr = filt_s[j];
        #pragma unroll
        for (int ls = 0; ls < 16; ++ls)
            acc[ls] = cmadd(acc[ls], fr[ls], v);
    }
    for (int g = 0; g < 4; ++g){
        if (jg == g){
            if (g == 0){
                #pragma unroll
                for (int ls = 0; ls < 16; ++ls) Tred[ls][mtc_l] = acc[ls];
            } else {
                #pragma unroll
                for (int ls = 0; ls < 16; ++ls){
                    float2 tp = Tred[ls][mtc_l];
                    tp.x += acc[ls].x; tp.y += acc[ls].y;
                    Tred[ls][mtc_l] = tp;
                }
            }
        }
        __syncthreads();
    }
    float2* To = (float2*)T_g + (size_t)xi*16*256 + qtr*64;
    for (int w = 0; w < 4; ++w){
        int e = tid + 256*w;
        int ls = e >> 6, ml = e & 63;
        To[(size_t)ls*256 + ml] = Tred[ls][ml];
    }
}

// S_kernel: one block per xi, 256 threads. Phases 2+3.
// PK is staged through LDS in 8 chunks (2 ls-rows = 2048 float2 = 16 KB each)
// with register prefetch of the next chunk (T14 async-stage split).
__global__ __launch_bounds__(256)
void S_kernel(const float* __restrict__ T_g,      // [xi][16][256] complex
              const float* __restrict__ PK2,      // [ls][mt][qr][g] complex
              const float* __restrict__ W_k,      // [q][c][g][d] complex
              float* __restrict__ Vout)           // packed [xi][qr*16+d]
{
    __shared__ float2 T_s[16][256];    // 32768 B
    __shared__ float2 PKbuf[2048];     // 16384 B; overlaid by S_s after phase 2
    float2* S_s = PKbuf;               // [g][qr][c] = 1024 float2 (8 KB)

    const int tid = threadIdx.x;
    const int xi = blockIdx.x;

    // stage T (coalesced, independent)
    {
        const float2* src = (const float2*)T_g + (size_t)xi*16*256;
        float2* dst = &T_s[0][0];
        for (int e = tid; e < 16*256; e += 256) dst[e] = src[e];
    }

    const int qr = tid >> 4, c = tid & 15;
    const float2* PKg = (const float2*)PK2;

    float2 accg[4];
    #pragma unroll
    for (int g = 0; g < 4; ++g) accg[g] = make_float2(0.f, 0.f);

    // prefetch chunk 0 into registers
    float2 stg[8];
    #pragma unroll
    for (int u = 0; u < 8; ++u) stg[u] = PKg[tid + 256*u];

    for (int ch = 0; ch < 8; ++ch){
        __syncthreads();               // T_s ready (ch=0) / prev chunk compute done
        #pragma unroll
        for (int u = 0; u < 8; ++u) PKbuf[tid + 256*u] = stg[u];
        if (ch < 7){
            #pragma unroll
            for (int u = 0; u < 8; ++u) stg[u] = PKg[2048*(ch+1) + tid + 256*u];
        }
        __syncthreads();
        #pragma unroll
        for (int lsl = 0; lsl < 2; ++lsl){
            const int ls = ch*2 + lsl;
            #pragma unroll 4
            for (int mt = 0; mt < 16; ++mt){
                float2 tv = T_s[ls][mt*16 + c];
                // PKbuf[((lsl*16+mt)*16+qr)*4 + g], g=0..3 contiguous (32B run)
                const float2* pk = &PKbuf[((lsl*16 + mt)*16 + qr)*4];
                accg[0] = cmadd(accg[0], pk[0], tv);
                accg[1] = cmadd(accg[1], pk[1], tv);
                accg[2] = cmadd(accg[2], pk[2], tv);
                accg[3] = cmadd(accg[3], pk[3], tv);
            }
        }
    }
    __syncthreads();   // PKbuf dead; reuse as S_s

    #pragma unroll
    for (int g = 0; g < 4; ++g) S_s[(g*16 + qr)*16 + c] = accg[g];
    __syncthreads();

    // phase 3: Vout[qr][d] = sum_{g,c} S[g][qr][c]*W[q][c][g][d]
    {
        const int d = tid & 15;        // reuse qr from above (tid>>4)
        const int q = P2R_c[qr];
        float2 acc = make_float2(0.f, 0.f);
        const float2* Wb = (const float2*)W_k + (size_t)q*16*4*16 + d;
        #pragma unroll 4
        for (int cc = 0; cc < 16; ++cc){
            #pragma unroll
            for (int g = 0; g < 4; ++g){
                float2 sv = S_s[(g*16 + qr)*16 + cc];
                float2 wv = Wb[(cc*4 + g)*16];
                acc = cmadd(acc, sv, wv);
            }
        }
        ((float2*)Vout)[(size_t)xi*256 + tid] = acc;
    }
}

// unpack final packed V -> d_out (x,i,q,d,r,z), zeros at r >= DIMS[q]
__global__ void unpack_V_kernel(const float* __restrict__ Vp,
                                float* __restrict__ out){
    int idx = blockIdx.x*blockDim.x + threadIdx.x;
    if (idx >= XS*NP*4*16*7) return;
    int r  = idx % 7;
    int d  = (idx / 7) % 16;
    int q  = (idx / (7*16)) % 4;
    int xi = idx / (7*16*4);
    float2 v = make_float2(0.f, 0.f);
    if (r < DIMS_c[q]){
        v = ((const float2*)Vp)[(size_t)xi*256 + (OFF_c[q] + r)*16 + d];
    }
    ((float2*)out)[idx] = v;
}

extern "C" void kernel_launch(void* const* d_in, const int* in_sizes, int n_in,
                              void* d_out, int out_size, void* d_ws, size_t ws_size,
                              hipStream_t stream) {
    const float* X  = (const float*)d_in[0];
    // d_in[1] is 'l' (always 3, hardcoded)
    const float* V  = (const float*)d_in[2];
    const float* cg = (const float*)d_in[3];
    const float* f  = (const float*)d_in[4];
    const float* W  = (const float*)d_in[5];
    // d_in[6] is C4 (plain complex product, hardcoded)

    // ws layout (floats); total ~2.40M floats = 9.6 MB
    float* ws     = (float*)d_ws;
    float* cgf    = ws;                         // 4704
    float* PK2    = cgf   + 4704;               // 32768
    float* VbufA  = PK2   + 32768;              // 98304
    float* VbufB  = VbufA + 98304;              // 98304
    float* filt_g = VbufB + 98304;              // 192*96*16*2 = 589824
    float* T_g    = filt_g + 589824;            // 192*16*256*2 = 1572864

    prep_kernel<<<(PREP_TOTAL + 255)/256, 256, 0, stream>>>(cg, f, V, cgf, PK2, VbufA);

    float* bufs[2] = {VbufA, VbufB};
    int cur = 0;
    for (int k = 0; k < NLAY; ++k){
        const float* cgf_k = cgf + (size_t)k*16*49*2;
        const float* W_k   = W   + (size_t)k*4*16*4*16*2;
        filt_kernel<<<XS*NP, 256, 0, stream>>>(X, cgf_k, filt_g);
        T_kernel<<<XS*NP*4, 256, 0, stream>>>(filt_g, bufs[cur], T_g);
        S_kernel<<<XS*NP, 256, 0, stream>>>(T_g, PK2, W_k, bufs[cur^1]);
        cur ^= 1;
    }
    unpack_V_kernel<<<(XS*NP*4*16*7 + 255)/256, 256, 0, stream>>>(bufs[cur], (float*)d_out);
}

// Round 7
// 177.018 us; speedup vs baseline: 2.4065x; 1.0698x over previous
//
#include <hip/hip_runtime.h>
#include <hip/hip_bf16.h>

// Problem constants (shapes fixed by the reference)
#define XS   2
#define NP   96
#define NLAY 3
#define NXI  (XS*NP)   // 192
// L_INPUT = 3, DIMS = (1,3,5,7), MAX_DIM = 7, NUM_CG = 4, NUM_CH = 16

// packed (rep,dim) index tables: 16 = 1+3+5+7 entries
__constant__ int P2R_c[16] = {0, 1,1,1, 2,2,2,2,2, 3,3,3,3,3,3,3};
__constant__ int P2D_c[16] = {0, 0,1,2, 0,1,2,3,4, 0,1,2,3,4,5,6};
__constant__ int DIMS_c[4] = {1,3,5,7};
__constant__ int OFF_c[4]  = {0,1,4,9};

__device__ inline float2 cmadd(float2 acc, float2 a, float2 b){
    acc.x += a.x*b.x - a.y*b.y;
    acc.y += a.x*b.y + a.y*b.x;
    return acc;
}

// One prep kernel, three flat ranges:
//  [0, 2352)            cgf[k][qr][s][t] = sum_g cg[g,3,s,3,t,q,r]*f[k,q,g]
//  [2352, 2352+16384)   PK2[ls][mt][qr][g] = cg[g,l,s,m,t,q,r]  (g innermost -> 32B runs)
//  [18736, 18736+49152) pack V -> Vp[x][j][mt16][c16]
#define PREP_TOTAL (2352 + 16384 + 49152)
__global__ void prep_kernel(const float* __restrict__ cg,
                            const float* __restrict__ f,
                            const float* __restrict__ Vin,
                            float* __restrict__ cgf,
                            float* __restrict__ PK2,
                            float* __restrict__ Vp){
    int idx = blockIdx.x*256 + threadIdx.x;
    if (idx < 2352){
        int k  = idx / (16*49);
        int rem = idx % (16*49);
        int qr = rem / 49;
        int st = rem % 49;
        int s = st / 7, t = st % 7;
        int q = P2R_c[qr], r = P2D_c[qr];
        float2 acc = make_float2(0.f, 0.f);
        for (int g = 0; g < 4; ++g){
            const float* cgp = cg + (((((((size_t)g*4+3)*7 + s)*4 + 3)*7 + t)*4 + q)*7 + r)*2;
            const float* fp  = f + ((k*4 + q)*4 + g)*2;
            acc = cmadd(acc, make_float2(cgp[0], cgp[1]), make_float2(fp[0], fp[1]));
        }
        cgf[idx*2]   = acc.x;
        cgf[idx*2+1] = acc.y;
    } else if (idx < 2352 + 16384){
        int id = idx - 2352;           // = ((ls*16+mt)*16+qr)*4+g
        int g  = id & 3;
        int qr = (id >> 2) & 15;
        int mt = (id >> 6) & 15;
        int ls = (id >> 10) & 15;
        int l = P2R_c[ls], s = P2D_c[ls];
        int m = P2R_c[mt], t = P2D_c[mt];
        int q = P2R_c[qr], r = P2D_c[qr];
        size_t co = (((((((size_t)g*4 + l)*7 + s)*4 + m)*7 + t)*4 + q)*7 + r);
        PK2[id*2]   = cg[co*2];
        PK2[id*2+1] = cg[co*2+1];
    } else if (idx < PREP_TOTAL){
        int id = idx - 18736;          // = (xj*16+mt)*16+c
        int c  = id & 15;
        int mt = (id >> 4) & 15;
        int xj = id >> 8;
        int m = P2R_c[mt], t = P2D_c[mt];
        const float* p = Vin + ((((size_t)xj*4 + m)*16 + c)*7 + t)*2;
        Vp[id*2]   = p[0];
        Vp[id*2+1] = p[1];
    }
}

// filt_all_kernel: grid 3*192 (layer k, point xi), 256 threads.
// Filters depend only on X and layer params -> computed ONCE for all layers.
// filt_g[k][xi][j][ls] = [l==3]*dX[s] + sum_s dX[s]*(sum_t cgf_k[ls][s][t]*dX[t])
__global__ __launch_bounds__(256)
void filt_all_kernel(const float* __restrict__ X,
                     const float* __restrict__ cgf,     // [k][16][49] complex
                     float* __restrict__ filt_g)        // [k][xi][96][16] complex
{
    __shared__ float2 cgf_s[784];      // 6272 B
    __shared__ float2 dX_s[NP][7];     // 5376 B

    const int tid = threadIdx.x;
    const int k  = blockIdx.x / NXI;
    const int xi = blockIdx.x % NXI;
    const int x = xi / NP, i = xi % NP;

    const float2* cgf_k = (const float2*)cgf + (size_t)k*784;
    for (int u = tid; u < 784; u += 256) cgf_s[u] = cgf_k[u];
    for (int e = tid; e < NP*7; e += 256){
        int j = e / 7, s = e % 7;
        const float* Xj = X + (((size_t)x*NP + j)*7 + s)*2;
        const float* Xi = X + (((size_t)x*NP + i)*7 + s)*2;
        dX_s[j][s] = make_float2(Xj[0]-Xi[0], Xj[1]-Xi[1]);
    }
    __syncthreads();

    float2* out = (float2*)filt_g + (size_t)blockIdx.x*NP*16;
    for (int e = tid; e < NP*16; e += 256){
        int j = e >> 4, qr = e & 15;
        const float2* cb = cgf_s + qr*49;
        float2 acc = make_float2(0.f, 0.f);
        #pragma unroll
        for (int s = 0; s < 7; ++s){
            float2 inner = make_float2(0.f, 0.f);
            #pragma unroll
            for (int t = 0; t < 7; ++t)
                inner = cmadd(inner, cb[s*7 + t], dX_s[j][t]);
            acc = cmadd(acc, dX_s[j][s], inner);
        }
        if (qr >= 9){ float2 dv = dX_s[j][qr-9]; acc.x += dv.x; acc.y += dv.y; }
        out[e] = acc;
    }
}

// TS_kernel: one block per xi, 512 threads (8 waves/CU). Fuses the j-contraction
// (T, LDS-resident) with the cg contraction (S) and the W channel mix.
__global__ __launch_bounds__(512)
void TS_kernel(const float* __restrict__ filt_gk,  // [xi][96][16] complex (layer k slice)
               const float* __restrict__ PK2,      // [ls][mt][qr][g] complex
               const float* __restrict__ W_k,      // [q][c][g][d] complex
               const float* __restrict__ Vin,      // packed [x][j][mtc]
               float* __restrict__ Vout)           // packed [xi][qr*16+d]
{
    __shared__ float2 filt_s[NP][16];  // 12288 B
    __shared__ float2 T_s[16][256];    // 32768 B
    __shared__ float2 PKbuf[2048];     // 16384 B; reused as S_s after phase S
    float2* S_s = PKbuf;               // [g][qr][c] = 1024 float2

    const int tid = threadIdx.x;
    const int xi = blockIdx.x;
    const int x = xi / NP;

    // stage filters for this xi (24 KB, L2-hit)
    {
        const float2* src = (const float2*)filt_gk + (size_t)xi*NP*16;
        float2* dst = &filt_s[0][0];
        for (int e = tid; e < NP*16; e += 512) dst[e] = src[e];
    }

    // prefetch PK chunk 0 into registers now: latency hides under the T phase
    const float2* PKg = (const float2*)PK2;
    float2 stg[4];
    #pragma unroll
    for (int u = 0; u < 4; ++u) stg[u] = PKg[tid + 512*u];

    __syncthreads();

    // ---- phase T: T[ls][mtc] = sum_j filt[j][ls]*Vin[x][j][mtc], 2-way j-split
    {
        const int jg  = tid >> 8;      // 0..1
        const int mtc = tid & 255;
        const float2* Vb = (const float2*)Vin + (size_t)x*NP*256 + mtc;
        float2 acc[16];
        #pragma unroll
        for (int u = 0; u < 16; ++u) acc[u] = make_float2(0.f, 0.f);
        const int j0 = jg*48;
        #pragma unroll 8
        for (int jj = 0; jj < 48; ++jj){
            const int j = j0 + jj;
            float2 v = Vb[(size_t)j*256];
            const float2* fr = filt_s[j];
            #pragma unroll
            for (int ls = 0; ls < 16; ++ls)
                acc[ls] = cmadd(acc[ls], fr[ls], v);
        }
        if (jg == 0){
            #pragma unroll
            for (int ls = 0; ls < 16; ++ls) T_s[ls][mtc] = acc[ls];
        }
        __syncthreads();
        if (jg == 1){
            #pragma unroll
            for (int ls = 0; ls < 16; ++ls){
                float2 tp = T_s[ls][mtc];
                tp.x += acc[ls].x; tp.y += acc[ls].y;
                T_s[ls][mtc] = tp;
            }
        }
        // sync happens at top of the S loop
    }

    // ---- phase S: S[g][qr][c] = sum_{ls,mt} PK[ls][mt][qr][g]*T[ls][mt][c]
    // 2-way mt-split (h), PK staged through LDS in 8 chunks of 2 ls-rows,
    // register prefetch of the next chunk.
    const int h  = tid >> 8;           // 0..1 -> mt in [8h, 8h+8)
    const int qr = (tid >> 4) & 15;
    const int c  = tid & 15;

    float2 accg[4];
    #pragma unroll
    for (int g = 0; g < 4; ++g) accg[g] = make_float2(0.f, 0.f);

    for (int ch = 0; ch < 8; ++ch){
        __syncthreads();               // T_s ready (ch=0) / prev chunk compute done
        #pragma unroll
        for (int u = 0; u < 4; ++u) PKbuf[tid + 512*u] = stg[u];
        if (ch < 7){
            #pragma unroll
            for (int u = 0; u < 4; ++u) stg[u] = PKg[2048*(ch+1) + tid + 512*u];
        }
        __syncthreads();
        #pragma unroll
        for (int lsl = 0; lsl < 2; ++lsl){
            const int ls = ch*2 + lsl;
            #pragma unroll 4
            for (int mtl = 0; mtl < 8; ++mtl){
                const int mt = h*8 + mtl;
                float2 tv = T_s[ls][mt*16 + c];
                const float2* pk = &PKbuf[((lsl*16 + mt)*16 + qr)*4];
                accg[0] = cmadd(accg[0], pk[0], tv);
                accg[1] = cmadd(accg[1], pk[1], tv);
                accg[2] = cmadd(accg[2], pk[2], tv);
                accg[3] = cmadd(accg[3], pk[3], tv);
            }
        }
    }
    __syncthreads();   // PKbuf dead; reuse as S_s

    if (h == 0){
        #pragma unroll
        for (int g = 0; g < 4; ++g) S_s[(g*16 + qr)*16 + c] = accg[g];
    }
    __syncthreads();
    if (h == 1){
        #pragma unroll
        for (int g = 0; g < 4; ++g){
            float2 sp = S_s[(g*16 + qr)*16 + c];
            sp.x += accg[g].x; sp.y += accg[g].y;
            S_s[(g*16 + qr)*16 + c] = sp;
        }
    }
    __syncthreads();

    // ---- phase W: Vout[qr][d] = sum_{g,c} S[g][qr][c]*W[q][c][g][d]
    if (tid < 256){
        const int d = tid & 15;        // qr = tid>>4 (same as above for tid<256)
        const int q = P2R_c[qr];
        float2 acc = make_float2(0.f, 0.f);
        const float2* Wb = (const float2*)W_k + (size_t)q*16*4*16 + d;
        #pragma unroll 4
        for (int cc = 0; cc < 16; ++cc){
            #pragma unroll
            for (int g = 0; g < 4; ++g){
                float2 sv = S_s[(g*16 + qr)*16 + cc];
                float2 wv = Wb[(cc*4 + g)*16];
                acc = cmadd(acc, sv, wv);
            }
        }
        ((float2*)Vout)[(size_t)xi*256 + tid] = acc;
    }
}

// unpack final packed V -> d_out (x,i,q,d,r,z), zeros at r >= DIMS[q]
__global__ void unpack_V_kernel(const float* __restrict__ Vp,
                                float* __restrict__ out){
    int idx = blockIdx.x*blockDim.x + threadIdx.x;
    if (idx >= XS*NP*4*16*7) return;
    int r  = idx % 7;
    int d  = (idx / 7) % 16;
    int q  = (idx / (7*16)) % 4;
    int xi = idx / (7*16*4);
    float2 v = make_float2(0.f, 0.f);
    if (r < DIMS_c[q]){
        v = ((const float2*)Vp)[(size_t)xi*256 + (OFF_c[q] + r)*16 + d];
    }
    ((float2*)out)[idx] = v;
}

extern "C" void kernel_launch(void* const* d_in, const int* in_sizes, int n_in,
                              void* d_out, int out_size, void* d_ws, size_t ws_size,
                              hipStream_t stream) {
    const float* X  = (const float*)d_in[0];
    // d_in[1] is 'l' (always 3, hardcoded)
    const float* V  = (const float*)d_in[2];
    const float* cg = (const float*)d_in[3];
    const float* f  = (const float*)d_in[4];
    const float* W  = (const float*)d_in[5];
    // d_in[6] is C4 (plain complex product, hardcoded)

    // ws layout (floats); total ~2.0M floats = 8.0 MB
    float* ws     = (float*)d_ws;
    float* cgf    = ws;                         // 3*784*2   = 4704
    float* PK2    = cgf   + 4704;               // 16384*2   = 32768
    float* VbufA  = PK2   + 32768;              // 192*256*2 = 98304
    float* VbufB  = VbufA + 98304;              // 98304
    float* filt_g = VbufB + 98304;              // 3*192*96*16*2 = 1769472

    prep_kernel<<<(PREP_TOTAL + 255)/256, 256, 0, stream>>>(cg, f, V, cgf, PK2, VbufA);
    filt_all_kernel<<<NLAY*NXI, 256, 0, stream>>>(X, cgf, filt_g);

    float* bufs[2] = {VbufA, VbufB};
    int cur = 0;
    for (int k = 0; k < NLAY; ++k){
        const float* filt_gk = filt_g + (size_t)k*NXI*NP*16*2;
        const float* W_k     = W      + (size_t)k*4*16*4*16*2;
        TS_kernel<<<NXI, 512, 0, stream>>>(filt_gk, PK2, W_k, bufs[cur], bufs[cur^1]);
        cur ^= 1;
    }
    unpack_V_kernel<<<(XS*NP*4*16*7 + 255)/256, 256, 0, stream>>>(bufs[cur], (float*)d_out);
}

// Round 8
// 147.054 us; speedup vs baseline: 2.8969x; 1.2038x over previous
//
#include <hip/hip_runtime.h>
#include <hip/hip_bf16.h>

// Problem constants (shapes fixed by the reference)
#define XS   2
#define NP   96
#define NLAY 3
#define NXI  (XS*NP)   // 192
// L_INPUT = 3, DIMS = (1,3,5,7), MAX_DIM = 7, NUM_CG = 4, NUM_CH = 16

// packed (rep,dim) index tables: 16 = 1+3+5+7 entries
__constant__ int P2R_c[16] = {0, 1,1,1, 2,2,2,2,2, 3,3,3,3,3,3,3};
__constant__ int P2D_c[16] = {0, 0,1,2, 0,1,2,3,4, 0,1,2,3,4,5,6};
__constant__ int DIMS_c[4] = {1,3,5,7};
__constant__ int OFF_c[4]  = {0,1,4,9};

__device__ inline float2 cmadd(float2 acc, float2 a, float2 b){
    acc.x += a.x*b.x - a.y*b.y;
    acc.y += a.x*b.y + a.y*b.x;
    return acc;
}

// One prep kernel, three flat ranges:
//  [0, 2352)            cgf[k][qr][s][t] = sum_g cg[g,3,s,3,t,q,r]*f[k,q,g]
//  [2352, 2352+16384)   PK2[ls][mt][qr][g] = cg[g,l,s,m,t,q,r]  (g innermost -> 32B runs)
//  [18736, 18736+49152) pack V -> Vp[x][j][mt16][c16]
#define PREP_TOTAL (2352 + 16384 + 49152)
__global__ void prep_kernel(const float* __restrict__ cg,
                            const float* __restrict__ f,
                            const float* __restrict__ Vin,
                            float* __restrict__ cgf,
                            float* __restrict__ PK2,
                            float* __restrict__ Vp){
    int idx = blockIdx.x*256 + threadIdx.x;
    if (idx < 2352){
        int k  = idx / (16*49);
        int rem = idx % (16*49);
        int qr = rem / 49;
        int st = rem % 49;
        int s = st / 7, t = st % 7;
        int q = P2R_c[qr], r = P2D_c[qr];
        float2 acc = make_float2(0.f, 0.f);
        for (int g = 0; g < 4; ++g){
            const float* cgp = cg + (((((((size_t)g*4+3)*7 + s)*4 + 3)*7 + t)*4 + q)*7 + r)*2;
            const float* fp  = f + ((k*4 + q)*4 + g)*2;
            acc = cmadd(acc, make_float2(cgp[0], cgp[1]), make_float2(fp[0], fp[1]));
        }
        cgf[idx*2]   = acc.x;
        cgf[idx*2+1] = acc.y;
    } else if (idx < 2352 + 16384){
        int id = idx - 2352;           // = ((ls*16+mt)*16+qr)*4+g
        int g  = id & 3;
        int qr = (id >> 2) & 15;
        int mt = (id >> 6) & 15;
        int ls = (id >> 10) & 15;
        int l = P2R_c[ls], s = P2D_c[ls];
        int m = P2R_c[mt], t = P2D_c[mt];
        int q = P2R_c[qr], r = P2D_c[qr];
        size_t co = (((((((size_t)g*4 + l)*7 + s)*4 + m)*7 + t)*4 + q)*7 + r);
        PK2[id*2]   = cg[co*2];
        PK2[id*2+1] = cg[co*2+1];
    } else if (idx < PREP_TOTAL){
        int id = idx - 18736;          // = (xj*16+mt)*16+c
        int c  = id & 15;
        int mt = (id >> 4) & 15;
        int xj = id >> 8;
        int m = P2R_c[mt], t = P2D_c[mt];
        const float* p = Vin + ((((size_t)xj*4 + m)*16 + c)*7 + t)*2;
        Vp[id*2]   = p[0];
        Vp[id*2+1] = p[1];
    }
}

// filt_all_kernel: grid 3*192 (layer k, point xi), 256 threads.
__global__ __launch_bounds__(256)
void filt_all_kernel(const float* __restrict__ X,
                     const float* __restrict__ cgf,     // [k][16][49] complex
                     float* __restrict__ filt_g)        // [k][xi][96][16] complex
{
    __shared__ float2 cgf_s[784];      // 6272 B
    __shared__ float2 dX_s[NP][7];     // 5376 B

    const int tid = threadIdx.x;
    const int k  = blockIdx.x / NXI;
    const int xi = blockIdx.x % NXI;
    const int x = xi / NP, i = xi % NP;

    const float2* cgf_k = (const float2*)cgf + (size_t)k*784;
    for (int u = tid; u < 784; u += 256) cgf_s[u] = cgf_k[u];
    for (int e = tid; e < NP*7; e += 256){
        int j = e / 7, s = e % 7;
        const float* Xj = X + (((size_t)x*NP + j)*7 + s)*2;
        const float* Xi = X + (((size_t)x*NP + i)*7 + s)*2;
        dX_s[j][s] = make_float2(Xj[0]-Xi[0], Xj[1]-Xi[1]);
    }
    __syncthreads();

    float2* out = (float2*)filt_g + (size_t)blockIdx.x*NP*16;
    for (int e = tid; e < NP*16; e += 256){
        int j = e >> 4, qr = e & 15;
        const float2* cb = cgf_s + qr*49;
        float2 acc = make_float2(0.f, 0.f);
        #pragma unroll
        for (int s = 0; s < 7; ++s){
            float2 inner = make_float2(0.f, 0.f);
            #pragma unroll
            for (int t = 0; t < 7; ++t)
                inner = cmadd(inner, cb[s*7 + t], dX_s[j][t]);
            acc = cmadd(acc, dX_s[j][s], inner);
        }
        if (qr >= 9){ float2 dv = dX_s[j][qr-9]; acc.x += dv.x; acc.y += dv.y; }
        out[e] = acc;
    }
}

// TS_kernel: one block per xi, 512 threads. Register-tiled T (4x4) and S (2qr x 4g).
__global__ __launch_bounds__(512)
void TS_kernel(const float* __restrict__ filt_gk,  // [xi][96][16] complex
               const float* __restrict__ PK2,      // [ls][mt][qr][g] complex
               const float* __restrict__ W_k,      // [q][c][g][d] complex
               const float* __restrict__ Vin,      // packed [x][j][mtc]
               float* __restrict__ Vout)           // packed [xi][qr*16+d]
{
    __shared__ __align__(16) float2 filt_s[NP][16];  // 12 KB
    __shared__ __align__(16) float2 T_s[16][256];    // 32 KB
    __shared__ __align__(16) float2 PKbuf[4096];     // 32 KB; reused as S_s after phase S
    float2* S_s = PKbuf;               // [g][qr][c] = 1024 float2

    const int tid = threadIdx.x;
    const int xi = blockIdx.x;
    const int x = xi / NP;

    // stage filters for this xi (24 KB, L2-hit)
    {
        const float2* src = (const float2*)filt_gk + (size_t)xi*NP*16;
        float2* dst = &filt_s[0][0];
        for (int e = tid; e < NP*16; e += 512) dst[e] = src[e];
    }
    __syncthreads();

    // ---- phase T: T[ls][col] = sum_j filt[j][ls]*V[j][col], 4x4 register tile,
    // 2-way j-split. Wave layout: lanes = 16 colq_lo x 4 lsq (filt rows distinct
    // across lanes -> full-width LDS reads; V reads coalesced 512B/wave).
    const int jg   = tid >> 8;                        // 0..1
    const int rem  = tid & 255;
    const int lsq  = (rem >> 4) & 3;                  // ls tile: lsq*4..+4
    const int colq = (rem & 15) | ((rem >> 6) << 4);  // col tile: colq*4..+4
    float2 stg[8];                                    // PK prefetch regs
    {
        const float4* F4 = (const float4*)&filt_s[0][0];  // j row = 8 float4
        const float4* V4 = (const float4*)((const float2*)Vin + (size_t)x*NP*256); // j row = 128 float4
        float2 acc[4][4];
        #pragma unroll
        for (int u = 0; u < 4; ++u)
            #pragma unroll
            for (int v = 0; v < 4; ++v) acc[u][v] = make_float2(0.f, 0.f);
        const int j0 = jg*48;
        #pragma unroll 2
        for (int jj = 0; jj < 48; ++jj){
            const int j = j0 + jj;
            float4 fa = F4[j*8 + lsq*2];
            float4 fb = F4[j*8 + lsq*2 + 1];
            float4 va = V4[j*128 + colq*2];
            float4 vb = V4[j*128 + colq*2 + 1];
            float2 f0 = make_float2(fa.x, fa.y), f1 = make_float2(fa.z, fa.w);
            float2 f2 = make_float2(fb.x, fb.y), f3 = make_float2(fb.z, fb.w);
            float2 v0 = make_float2(va.x, va.y), v1 = make_float2(va.z, va.w);
            float2 v2 = make_float2(vb.x, vb.y), v3 = make_float2(vb.z, vb.w);
            acc[0][0]=cmadd(acc[0][0],f0,v0); acc[0][1]=cmadd(acc[0][1],f0,v1);
            acc[0][2]=cmadd(acc[0][2],f0,v2); acc[0][3]=cmadd(acc[0][3],f0,v3);
            acc[1][0]=cmadd(acc[1][0],f1,v0); acc[1][1]=cmadd(acc[1][1],f1,v1);
            acc[1][2]=cmadd(acc[1][2],f1,v2); acc[1][3]=cmadd(acc[1][3],f1,v3);
            acc[2][0]=cmadd(acc[2][0],f2,v0); acc[2][1]=cmadd(acc[2][1],f2,v1);
            acc[2][2]=cmadd(acc[2][2],f2,v2); acc[2][3]=cmadd(acc[2][3],f2,v3);
            acc[3][0]=cmadd(acc[3][0],f3,v0); acc[3][1]=cmadd(acc[3][1],f3,v1);
            acc[3][2]=cmadd(acc[3][2],f3,v2); acc[3][3]=cmadd(acc[3][3],f3,v3);
        }

        // prefetch PK chunk 0 now (latency hides under the T_s reduction)
        const float2* PKg = (const float2*)PK2;
        #pragma unroll
        for (int u = 0; u < 8; ++u) stg[u] = PKg[tid + 512*u];

        // jg reduction into T_s
        float4* Ts4 = (float4*)&T_s[0][0];   // row = 128 float4
        if (jg == 0){
            #pragma unroll
            for (int u = 0; u < 4; ++u){
                Ts4[(lsq*4+u)*128 + colq*2]     = make_float4(acc[u][0].x, acc[u][0].y, acc[u][1].x, acc[u][1].y);
                Ts4[(lsq*4+u)*128 + colq*2 + 1] = make_float4(acc[u][2].x, acc[u][2].y, acc[u][3].x, acc[u][3].y);
            }
        }
        __syncthreads();
        if (jg == 1){
            #pragma unroll
            for (int u = 0; u < 4; ++u){
                #pragma unroll
                for (int v = 0; v < 4; ++v){
                    float2 tp = T_s[lsq*4+u][colq*4+v];
                    tp.x += acc[u][v].x; tp.y += acc[u][v].y;
                    T_s[lsq*4+u][colq*4+v] = tp;
                }
            }
        }
        // barrier at top of chunk loop guards the RMW
    }

    // ---- phase S: S[g][qr][c] = sum_{ls,mt} PK[ls][mt][qr][g]*T[ls][mt][c]
    // thread = (mth4, qrp8, c16): owns qr pair {qrp, qrp+8} x 4 g, mt in [mth*4,+4).
    // PK staged in 4 chunks of 4 ls-rows (32 KB) with register prefetch.
    const int mth = tid >> 7;          // 0..3
    const int qrp = (tid >> 4) & 7;
    const int c   = tid & 15;
    const float2* PKg = (const float2*)PK2;

    float2 accg[2][4];
    #pragma unroll
    for (int p = 0; p < 2; ++p)
        #pragma unroll
        for (int g = 0; g < 4; ++g) accg[p][g] = make_float2(0.f, 0.f);

    for (int ch = 0; ch < 4; ++ch){
        __syncthreads();               // T_s/RMW ready (ch=0) / prev chunk compute done
        #pragma unroll
        for (int u = 0; u < 8; ++u) PKbuf[tid + 512*u] = stg[u];
        if (ch < 3){
            #pragma unroll
            for (int u = 0; u < 8; ++u) stg[u] = PKg[4096*(ch+1) + tid + 512*u];
        }
        __syncthreads();
        #pragma unroll
        for (int lsl = 0; lsl < 4; ++lsl){
            const int ls = ch*4 + lsl;
            #pragma unroll
            for (int mtl = 0; mtl < 4; ++mtl){
                const int mt = mth*4 + mtl;
                float2 tv = T_s[ls][mt*16 + c];
                const float2* pk0 = &PKbuf[((lsl*16 + mt)*16 + qrp)*4];
                const float2* pk1 = pk0 + 32;   // qr + 8
                accg[0][0] = cmadd(accg[0][0], pk0[0], tv);
                accg[0][1] = cmadd(accg[0][1], pk0[1], tv);
                accg[0][2] = cmadd(accg[0][2], pk0[2], tv);
                accg[0][3] = cmadd(accg[0][3], pk0[3], tv);
                accg[1][0] = cmadd(accg[1][0], pk1[0], tv);
                accg[1][1] = cmadd(accg[1][1], pk1[1], tv);
                accg[1][2] = cmadd(accg[1][2], pk1[2], tv);
                accg[1][3] = cmadd(accg[1][3], pk1[3], tv);
            }
        }
    }
    __syncthreads();   // PKbuf dead; reuse as S_s

    // 4-stage mth reduction into S_s[(g*16+qr)*16+c]
    for (int st = 0; st < 4; ++st){
        if (mth == st){
            #pragma unroll
            for (int p = 0; p < 2; ++p){
                const int qr_p = qrp + 8*p;
                if (st == 0){
                    #pragma unroll
                    for (int g = 0; g < 4; ++g) S_s[(g*16 + qr_p)*16 + c] = accg[p][g];
                } else {
                    #pragma unroll
                    for (int g = 0; g < 4; ++g){
                        float2 sp = S_s[(g*16 + qr_p)*16 + c];
                        sp.x += accg[p][g].x; sp.y += accg[p][g].y;
                        S_s[(g*16 + qr_p)*16 + c] = sp;
                    }
                }
            }
        }
        __syncthreads();
    }

    // ---- phase W: Vout[qr][d] = sum_{g,c} S[g][qr][c]*W[q][c][g][d]
    if (tid < 256){
        const int qr = tid >> 4, d = tid & 15;
        const int q = P2R_c[qr];
        float2 acc = make_float2(0.f, 0.f);
        const float2* Wb = (const float2*)W_k + (size_t)q*16*4*16 + d;
        #pragma unroll 4
        for (int cc = 0; cc < 16; ++cc){
            #pragma unroll
            for (int g = 0; g < 4; ++g){
                float2 sv = S_s[(g*16 + qr)*16 + cc];
                float2 wv = Wb[(cc*4 + g)*16];
                acc = cmadd(acc, sv, wv);
            }
        }
        ((float2*)Vout)[(size_t)xi*256 + tid] = acc;
    }
}

// unpack final packed V -> d_out (x,i,q,d,r,z), zeros at r >= DIMS[q]
__global__ void unpack_V_kernel(const float* __restrict__ Vp,
                                float* __restrict__ out){
    int idx = blockIdx.x*blockDim.x + threadIdx.x;
    if (idx >= XS*NP*4*16*7) return;
    int r  = idx % 7;
    int d  = (idx / 7) % 16;
    int q  = (idx / (7*16)) % 4;
    int xi = idx / (7*16*4);
    float2 v = make_float2(0.f, 0.f);
    if (r < DIMS_c[q]){
        v = ((const float2*)Vp)[(size_t)xi*256 + (OFF_c[q] + r)*16 + d];
    }
    ((float2*)out)[idx] = v;
}

extern "C" void kernel_launch(void* const* d_in, const int* in_sizes, int n_in,
                              void* d_out, int out_size, void* d_ws, size_t ws_size,
                              hipStream_t stream) {
    const float* X  = (const float*)d_in[0];
    // d_in[1] is 'l' (always 3, hardcoded)
    const float* V  = (const float*)d_in[2];
    const float* cg = (const float*)d_in[3];
    const float* f  = (const float*)d_in[4];
    const float* W  = (const float*)d_in[5];
    // d_in[6] is C4 (plain complex product, hardcoded)

    // ws layout (floats); total ~2.0M floats = 8.0 MB
    float* ws     = (float*)d_ws;
    float* cgf    = ws;                         // 3*784*2   = 4704
    float* PK2    = cgf   + 4704;               // 16384*2   = 32768
    float* VbufA  = PK2   + 32768;              // 192*256*2 = 98304
    float* VbufB  = VbufA + 98304;              // 98304
    float* filt_g = VbufB + 98304;              // 3*192*96*16*2 = 1769472

    prep_kernel<<<(PREP_TOTAL + 255)/256, 256, 0, stream>>>(cg, f, V, cgf, PK2, VbufA);
    filt_all_kernel<<<NLAY*NXI, 256, 0, stream>>>(X, cgf, filt_g);

    float* bufs[2] = {VbufA, VbufB};
    int cur = 0;
    for (int k = 0; k < NLAY; ++k){
        const float* filt_gk = filt_g + (size_t)k*NXI*NP*16*2;
        const float* W_k     = W      + (size_t)k*4*16*4*16*2;
        TS_kernel<<<NXI, 512, 0, stream>>>(filt_gk, PK2, W_k, bufs[cur], bufs[cur^1]);
        cur ^= 1;
    }
    unpack_V_kernel<<<(XS*NP*4*16*7 + 255)/256, 256, 0, stream>>>(bufs[cur], (float*)d_out);
}

// Round 9
// 141.982 us; speedup vs baseline: 3.0004x; 1.0357x over previous
//
#include <hip/hip_runtime.h>
#include <hip/hip_bf16.h>

// Problem constants (shapes fixed by the reference)
#define XS   2
#define NP   96
#define NLAY 3
#define NXI  (XS*NP)   // 192
// L_INPUT = 3, DIMS = (1,3,5,7), MAX_DIM = 7, NUM_CG = 4, NUM_CH = 16

// packed (rep,dim) index tables: 16 = 1+3+5+7 entries
__constant__ int P2R_c[16] = {0, 1,1,1, 2,2,2,2,2, 3,3,3,3,3,3,3};
__constant__ int P2D_c[16] = {0, 0,1,2, 0,1,2,3,4, 0,1,2,3,4,5,6};
__constant__ int DIMS_c[4] = {1,3,5,7};
__constant__ int OFF_c[4]  = {0,1,4,9};

__device__ inline float2 cmadd(float2 acc, float2 a, float2 b){
    acc.x += a.x*b.x - a.y*b.y;
    acc.y += a.x*b.y + a.y*b.x;
    return acc;
}

// One prep kernel, three flat ranges:
//  [0, 2352)            cgf[k][qr][s][t] = sum_g cg[g,3,s,3,t,q,r]*f[k,q,g]
//  [2352, 2352+16384)   PK2[ls][mt][qr][g] = cg[g,l,s,m,t,q,r]  (g innermost -> 32B runs)
//  [18736, 18736+49152) pack V -> Vp[x][j][mt16][c16]
#define PREP_TOTAL (2352 + 16384 + 49152)
__global__ void prep_kernel(const float* __restrict__ cg,
                            const float* __restrict__ f,
                            const float* __restrict__ Vin,
                            float* __restrict__ cgf,
                            float* __restrict__ PK2,
                            float* __restrict__ Vp){
    int idx = blockIdx.x*256 + threadIdx.x;
    if (idx < 2352){
        int k  = idx / (16*49);
        int rem = idx % (16*49);
        int qr = rem / 49;
        int st = rem % 49;
        int s = st / 7, t = st % 7;
        int q = P2R_c[qr], r = P2D_c[qr];
        float2 acc = make_float2(0.f, 0.f);
        for (int g = 0; g < 4; ++g){
            const float* cgp = cg + (((((((size_t)g*4+3)*7 + s)*4 + 3)*7 + t)*4 + q)*7 + r)*2;
            const float* fp  = f + ((k*4 + q)*4 + g)*2;
            acc = cmadd(acc, make_float2(cgp[0], cgp[1]), make_float2(fp[0], fp[1]));
        }
        cgf[idx*2]   = acc.x;
        cgf[idx*2+1] = acc.y;
    } else if (idx < 2352 + 16384){
        int id = idx - 2352;           // = ((ls*16+mt)*16+qr)*4+g
        int g  = id & 3;
        int qr = (id >> 2) & 15;
        int mt = (id >> 6) & 15;
        int ls = (id >> 10) & 15;
        int l = P2R_c[ls], s = P2D_c[ls];
        int m = P2R_c[mt], t = P2D_c[mt];
        int q = P2R_c[qr], r = P2D_c[qr];
        size_t co = (((((((size_t)g*4 + l)*7 + s)*4 + m)*7 + t)*4 + q)*7 + r);
        PK2[id*2]   = cg[co*2];
        PK2[id*2+1] = cg[co*2+1];
    } else if (idx < PREP_TOTAL){
        int id = idx - 18736;          // = (xj*16+mt)*16+c
        int c  = id & 15;
        int mt = (id >> 4) & 15;
        int xj = id >> 8;
        int m = P2R_c[mt], t = P2D_c[mt];
        const float* p = Vin + ((((size_t)xj*4 + m)*16 + c)*7 + t)*2;
        Vp[id*2]   = p[0];
        Vp[id*2+1] = p[1];
    }
}

// filt_all_kernel: grid 3*192 (layer k, point xi), 256 threads.
__global__ __launch_bounds__(256)
void filt_all_kernel(const float* __restrict__ X,
                     const float* __restrict__ cgf,     // [k][16][49] complex
                     float* __restrict__ filt_g)        // [k][xi][96][16] complex
{
    __shared__ float2 cgf_s[784];      // 6272 B
    __shared__ float2 dX_s[NP][7];     // 5376 B

    const int tid = threadIdx.x;
    const int k  = blockIdx.x / NXI;
    const int xi = blockIdx.x % NXI;
    const int x = xi / NP, i = xi % NP;

    const float2* cgf_k = (const float2*)cgf + (size_t)k*784;
    for (int u = tid; u < 784; u += 256) cgf_s[u] = cgf_k[u];
    for (int e = tid; e < NP*7; e += 256){
        int j = e / 7, s = e % 7;
        const float* Xj = X + (((size_t)x*NP + j)*7 + s)*2;
        const float* Xi = X + (((size_t)x*NP + i)*7 + s)*2;
        dX_s[j][s] = make_float2(Xj[0]-Xi[0], Xj[1]-Xi[1]);
    }
    __syncthreads();

    float2* out = (float2*)filt_g + (size_t)blockIdx.x*NP*16;
    for (int e = tid; e < NP*16; e += 256){
        int j = e >> 4, qr = e & 15;
        const float2* cb = cgf_s + qr*49;
        float2 acc = make_float2(0.f, 0.f);
        #pragma unroll
        for (int s = 0; s < 7; ++s){
            float2 inner = make_float2(0.f, 0.f);
            #pragma unroll
            for (int t = 0; t < 7; ++t)
                inner = cmadd(inner, cb[s*7 + t], dX_s[j][t]);
            acc = cmadd(acc, dX_s[j][s], inner);
        }
        if (qr >= 9){ float2 dv = dX_s[j][qr-9]; acc.x += dv.x; acc.y += dv.y; }
        out[e] = acc;
    }
}

// TS_kernel: grid 768 = (xi, c-quarter cq), 256 threads, 3 blocks/CU.
// Each block: T for its 64 cols (16 mt x 4 c), S for its 4 c, partial W
// atomically accumulated into Vout (zeroed beforehand).
__global__ __launch_bounds__(256)
void TS_kernel(const float* __restrict__ filt_gk,  // [xi][96][16] complex
               const float* __restrict__ PK2,      // [ls][mt][qr][g] complex
               const float* __restrict__ W_k,      // [q][c][g][d] complex
               const float* __restrict__ Vin,      // packed [x][j][mtc]
               float* __restrict__ Vout)           // packed [xi][qr*16+d], pre-zeroed
{
    __shared__ __align__(16) float2 filt_s[NP][16];  // 12288 B
    __shared__ __align__(16) float2 T_s[16][66];     // 8448 B (rows padded +2)
    __shared__ __align__(16) float2 PKbuf[4096];     // 32768 B; reused as S_s
    float2* S_s = PKbuf;               // [g][qr][cl] = 256 float2

    const int tid = threadIdx.x;
    const int xi = blockIdx.x >> 2;
    const int cq = blockIdx.x & 3;
    const int x  = xi / NP;

    // stage filters for this xi (24 KB, L2-hit)
    {
        const float2* src = (const float2*)filt_gk + (size_t)xi*NP*16;
        float2* dst = &filt_s[0][0];
        for (int e = tid; e < NP*16; e += 256) dst[e] = src[e];
    }
    __syncthreads();

    // ---- phase T: T[ls][col] = sum_j filt[j][ls]*V[j][mtc], 4x4 reg tile,
    // 4-way j-split. col = mt*4+cl (local), mtc = mt*16 + cq*4 + cl (global).
    const int jg   = tid >> 6;         // 0..3
    const int pos  = tid & 63;
    const int lsq  = pos >> 4;         // ls quad
    const int colq = pos & 15;         // = mt
    float2 stg[16];                    // PK prefetch regs
    {
        const float4* F4 = (const float4*)&filt_s[0][0];  // j row = 8 float4
        const float4* V4 = (const float4*)((const float2*)Vin + (size_t)x*NP*256);
        float2 acc[4][4];
        #pragma unroll
        for (int u = 0; u < 4; ++u)
            #pragma unroll
            for (int v = 0; v < 4; ++v) acc[u][v] = make_float2(0.f, 0.f);
        const int j0 = jg*24;
        const int vcol = colq*8 + cq*2;    // float4 units within 128-f4 row
        #pragma unroll 2
        for (int jj = 0; jj < 24; ++jj){
            const int j = j0 + jj;
            float4 fa = F4[j*8 + lsq*2];
            float4 fb = F4[j*8 + lsq*2 + 1];
            float4 va = V4[j*128 + vcol];
            float4 vb = V4[j*128 + vcol + 1];
            float2 f0 = make_float2(fa.x, fa.y), f1 = make_float2(fa.z, fa.w);
            float2 f2 = make_float2(fb.x, fb.y), f3 = make_float2(fb.z, fb.w);
            float2 v0 = make_float2(va.x, va.y), v1 = make_float2(va.z, va.w);
            float2 v2 = make_float2(vb.x, vb.y), v3 = make_float2(vb.z, vb.w);
            acc[0][0]=cmadd(acc[0][0],f0,v0); acc[0][1]=cmadd(acc[0][1],f0,v1);
            acc[0][2]=cmadd(acc[0][2],f0,v2); acc[0][3]=cmadd(acc[0][3],f0,v3);
            acc[1][0]=cmadd(acc[1][0],f1,v0); acc[1][1]=cmadd(acc[1][1],f1,v1);
            acc[1][2]=cmadd(acc[1][2],f1,v2); acc[1][3]=cmadd(acc[1][3],f1,v3);
            acc[2][0]=cmadd(acc[2][0],f2,v0); acc[2][1]=cmadd(acc[2][1],f2,v1);
            acc[2][2]=cmadd(acc[2][2],f2,v2); acc[2][3]=cmadd(acc[2][3],f2,v3);
            acc[3][0]=cmadd(acc[3][0],f3,v0); acc[3][1]=cmadd(acc[3][1],f3,v1);
            acc[3][2]=cmadd(acc[3][2],f3,v2); acc[3][3]=cmadd(acc[3][3],f3,v3);
        }

        // prefetch PK chunk 0 now (latency hides under the T_s reduction)
        const float2* PKg = (const float2*)PK2;
        #pragma unroll
        for (int u = 0; u < 16; ++u) stg[u] = PKg[tid + 256*u];

        // 4-stage jg reduction into T_s
        for (int st = 0; st < 4; ++st){
            if (jg == st){
                if (st == 0){
                    #pragma unroll
                    for (int u = 0; u < 4; ++u){
                        float4* Trow = (float4*)&T_s[lsq*4+u][0];  // 33 float4/row
                        Trow[colq*2]   = make_float4(acc[u][0].x, acc[u][0].y, acc[u][1].x, acc[u][1].y);
                        Trow[colq*2+1] = make_float4(acc[u][2].x, acc[u][2].y, acc[u][3].x, acc[u][3].y);
                    }
                } else {
                    #pragma unroll
                    for (int u = 0; u < 4; ++u){
                        #pragma unroll
                        for (int v = 0; v < 4; ++v){
                            float2 tp = T_s[lsq*4+u][colq*4+v];
                            tp.x += acc[u][v].x; tp.y += acc[u][v].y;
                            T_s[lsq*4+u][colq*4+v] = tp;
                        }
                    }
                }
            }
            __syncthreads();
        }
    }

    // ---- phase S: S[g][qr][cl] = sum_{ls,mt} PK[ls][mt][qr][g]*T[ls][mt*4+cl]
    // thread = (mth4, qr16, cl4); PK staged in 4 chunks of 4 ls-rows (32 KB).
    const int mth = tid >> 6;          // 0..3 -> mt in [mth*4, +4)
    const int qr  = (tid >> 2) & 15;
    const int cl  = tid & 3;
    const float2* PKg = (const float2*)PK2;

    float2 accg[4];
    #pragma unroll
    for (int g = 0; g < 4; ++g) accg[g] = make_float2(0.f, 0.f);

    for (int ch = 0; ch < 4; ++ch){
        if (ch) __syncthreads();       // prev chunk compute done
        #pragma unroll
        for (int u = 0; u < 16; ++u) PKbuf[tid + 256*u] = stg[u];
        if (ch < 3){
            #pragma unroll
            for (int u = 0; u < 16; ++u) stg[u] = PKg[4096*(ch+1) + tid + 256*u];
        }
        __syncthreads();
        #pragma unroll
        for (int lsl = 0; lsl < 4; ++lsl){
            const int ls = ch*4 + lsl;
            #pragma unroll
            for (int mtl = 0; mtl < 4; ++mtl){
                const int mt = mth*4 + mtl;
                float2 tv = T_s[ls][mt*4 + cl];
                const float2* pk = &PKbuf[((lsl*16 + mt)*16 + qr)*4];
                accg[0] = cmadd(accg[0], pk[0], tv);
                accg[1] = cmadd(accg[1], pk[1], tv);
                accg[2] = cmadd(accg[2], pk[2], tv);
                accg[3] = cmadd(accg[3], pk[3], tv);
            }
        }
    }
    __syncthreads();   // PKbuf dead; reuse as S_s

    // 4-stage mth reduction into S_s[(g*16+qr)*4+cl]
    for (int st = 0; st < 4; ++st){
        if (mth == st){
            if (st == 0){
                #pragma unroll
                for (int g = 0; g < 4; ++g) S_s[(g*16 + qr)*4 + cl] = accg[g];
            } else {
                #pragma unroll
                for (int g = 0; g < 4; ++g){
                    float2 sp = S_s[(g*16 + qr)*4 + cl];
                    sp.x += accg[g].x; sp.y += accg[g].y;
                    S_s[(g*16 + qr)*4 + cl] = sp;
                }
            }
        }
        __syncthreads();
    }

    // ---- phase W (partial over this cq): Vout[qr][d] += sum_{g,cl} S*W
    {
        const int qr2 = tid >> 4, d = tid & 15;
        const int q = P2R_c[qr2];
        float2 acc = make_float2(0.f, 0.f);
        const float2* Wb = (const float2*)W_k + (size_t)q*16*4*16 + d;
        #pragma unroll
        for (int c2 = 0; c2 < 4; ++c2){
            const int c = cq*4 + c2;
            #pragma unroll
            for (int g = 0; g < 4; ++g){
                float2 sv = S_s[(g*16 + qr2)*4 + c2];
                float2 wv = Wb[(c*4 + g)*16];
                acc = cmadd(acc, sv, wv);
            }
        }
        float* outp = (float*)Vout + ((size_t)xi*256 + tid)*2;
        atomicAdd(outp,     acc.x);
        atomicAdd(outp + 1, acc.y);
    }
}

// unpack final packed V -> d_out (x,i,q,d,r,z), zeros at r >= DIMS[q]
__global__ void unpack_V_kernel(const float* __restrict__ Vp,
                                float* __restrict__ out){
    int idx = blockIdx.x*blockDim.x + threadIdx.x;
    if (idx >= XS*NP*4*16*7) return;
    int r  = idx % 7;
    int d  = (idx / 7) % 16;
    int q  = (idx / (7*16)) % 4;
    int xi = idx / (7*16*4);
    float2 v = make_float2(0.f, 0.f);
    if (r < DIMS_c[q]){
        v = ((const float2*)Vp)[(size_t)xi*256 + (OFF_c[q] + r)*16 + d];
    }
    ((float2*)out)[idx] = v;
}

extern "C" void kernel_launch(void* const* d_in, const int* in_sizes, int n_in,
                              void* d_out, int out_size, void* d_ws, size_t ws_size,
                              hipStream_t stream) {
    const float* X  = (const float*)d_in[0];
    // d_in[1] is 'l' (always 3, hardcoded)
    const float* V  = (const float*)d_in[2];
    const float* cg = (const float*)d_in[3];
    const float* f  = (const float*)d_in[4];
    const float* W  = (const float*)d_in[5];
    // d_in[6] is C4 (plain complex product, hardcoded)

    // ws layout (floats)
    float* ws     = (float*)d_ws;
    float* cgf    = ws;                         // 3*784*2   = 4704
    float* PK2    = cgf   + 4704;               // 16384*2   = 32768
    float* VbufA  = PK2   + 32768;              // 192*256*2 = 98304
    float* VbufB  = VbufA + 98304;              // 98304
    float* filt_g = VbufB + 98304;              // 3*192*96*16*2 = 1769472

    const size_t vbytes = (size_t)98304 * sizeof(float);

    prep_kernel<<<(PREP_TOTAL + 255)/256, 256, 0, stream>>>(cg, f, V, cgf, PK2, VbufA);
    hipMemsetAsync(VbufB, 0, vbytes, stream);
    filt_all_kernel<<<NLAY*NXI, 256, 0, stream>>>(X, cgf, filt_g);

    const float* W0 = W;
    const float* W1 = W + (size_t)1*4*16*4*16*2;
    const float* W2 = W + (size_t)2*4*16*4*16*2;
    const float* f0 = filt_g;
    const float* f1 = filt_g + (size_t)1*NXI*NP*16*2;
    const float* f2 = filt_g + (size_t)2*NXI*NP*16*2;

    // layer 0: read A, accumulate into B (pre-zeroed)
    TS_kernel<<<NXI*4, 256, 0, stream>>>(f0, PK2, W0, VbufA, VbufB);
    hipMemsetAsync(VbufA, 0, vbytes, stream);   // after L0 finished reading A
    // layer 1: read B, accumulate into A
    TS_kernel<<<NXI*4, 256, 0, stream>>>(f1, PK2, W1, VbufB, VbufA);
    hipMemsetAsync(VbufB, 0, vbytes, stream);   // after L1 finished reading B
    // layer 2: read A, accumulate into B
    TS_kernel<<<NXI*4, 256, 0, stream>>>(f2, PK2, W2, VbufA, VbufB);

    unpack_V_kernel<<<(XS*NP*4*16*7 + 255)/256, 256, 0, stream>>>(VbufB, (float*)d_out);
}